// Round 1
// baseline (1766.150 us; speedup 1.0000x reference)
//
#include <hip/hip_runtime.h>

#define DIM 512
#define HEADS 8
#define DK 64
#define BATCH 4
#define SEQ 2048
#define MROWS (BATCH * SEQ)   // 8192

// ---------------------------------------------------------------------------
// Kernel 1: xp = x + concat(emb1[coord1], emb2[coord2])
// one thread per float4; 8192 rows * 128 float4/row = 1,048,576 threads
// ---------------------------------------------------------------------------
__global__ __launch_bounds__(256) void pos_add_kernel(
    const float* __restrict__ x,
    const int* __restrict__ c1, const int* __restrict__ c2,
    const float* __restrict__ e1, const float* __restrict__ e2,
    float* __restrict__ xp) {
  int gid = blockIdx.x * blockDim.x + threadIdx.x;
  int row = gid >> 7;          // 128 float4 per row
  int col = (gid & 127) * 4;   // float offset in row
  float4 p;
  if (col < 256) {
    int idx = c1[row];
    p = *(const float4*)(e1 + (size_t)idx * 256 + col);
  } else {
    int idx = c2[row];
    p = *(const float4*)(e2 + (size_t)idx * 256 + (col - 256));
  }
  float4 xv = *(const float4*)(x + (size_t)row * DIM + col);
  float4 o;
  o.x = xv.x + p.x; o.y = xv.y + p.y; o.z = xv.z + p.z; o.w = xv.w + p.w;
  *(float4*)(xp + (size_t)row * DIM + col) = o;
}

// ---------------------------------------------------------------------------
// Kernel 2: C[M,512] = A[M,512] @ W[512,512] + bias (+ optional leaky_relu)
// BM=BN=64, BK=16, 256 threads, 4x4 micro-tile per thread.
// ---------------------------------------------------------------------------
template <bool LEAKY>
__global__ __launch_bounds__(256) void gemm_bias_kernel(
    const float* __restrict__ A, const float* __restrict__ W,
    const float* __restrict__ bias, float* __restrict__ C) {
  const int BK = 16;
  __shared__ float As[BK][68];   // [k][m], padded 64->68 to soften write conflicts
  __shared__ float Bs[BK][64];   // [k][n]

  int t = threadIdx.x;
  int m0 = blockIdx.y * 64;
  int n0 = blockIdx.x * 64;
  int ty = t >> 4;        // 0..15
  int tx = t & 15;        // 0..15
  int row_a = t >> 2;            // 0..63
  int col_a = (t & 3) * 4;       // 0,4,8,12
  int row_b = t >> 4;            // 0..15
  int col_b = (t & 15) * 4;      // 0..60

  float acc[4][4] = {};

  for (int k0 = 0; k0 < 512; k0 += BK) {
    __syncthreads();
    float4 av = *(const float4*)(A + (size_t)(m0 + row_a) * 512 + k0 + col_a);
    As[col_a + 0][row_a] = av.x;
    As[col_a + 1][row_a] = av.y;
    As[col_a + 2][row_a] = av.z;
    As[col_a + 3][row_a] = av.w;
    *(float4*)(&Bs[row_b][col_b]) =
        *(const float4*)(W + (size_t)(k0 + row_b) * 512 + n0 + col_b);
    __syncthreads();

#pragma unroll
    for (int k = 0; k < BK; k++) {
      float4 a = *(const float4*)(&As[k][ty * 4]);
      float4 b = *(const float4*)(&Bs[k][tx * 4]);
      float ar[4] = {a.x, a.y, a.z, a.w};
      float br[4] = {b.x, b.y, b.z, b.w};
#pragma unroll
      for (int i = 0; i < 4; i++)
#pragma unroll
        for (int j = 0; j < 4; j++) acc[i][j] += ar[i] * br[j];
    }
  }

#pragma unroll
  for (int i = 0; i < 4; i++) {
    int m = m0 + ty * 4 + i;
    int n = n0 + tx * 4;
    float4 ov;
    float vv[4];
#pragma unroll
    for (int j = 0; j < 4; j++) {
      float v = acc[i][j] + bias[n + j];
      if (LEAKY) v = (v >= 0.f) ? v : 0.2f * v;
      vv[j] = v;
    }
    ov.x = vv[0]; ov.y = vv[1]; ov.z = vv[2]; ov.w = vv[3];
    *(float4*)(C + (size_t)m * 512 + n) = ov;
  }
}

// ---------------------------------------------------------------------------
// Kernel 3: flash attention.  q,k,v,out: [B,S,DIM] viewed as [B,S,H,64].
// grid = B*H*8 = 256 blocks, 256 threads (4 waves).
// Block handles (b, h, 256 q-rows). Wave handles 64 q-rows.
// Lane: grp = lane&15 -> 4 consecutive q-rows; part = lane>>4 -> dims [16*part,+16).
// Score dot = partial over 16 dims + butterfly shfl_xor(16), shfl_xor(32).
// ---------------------------------------------------------------------------
__global__ __launch_bounds__(256, 1) void attn_kernel(
    const float* __restrict__ q, const float* __restrict__ k,
    const float* __restrict__ v, float* __restrict__ out) {
  __shared__ float Ks[64][64];
  __shared__ float Vs[64][64];

  int t = threadIdx.x;
  int blk = blockIdx.x;
  int qt = blk & 7;
  int h = (blk >> 3) & 7;
  int b = blk >> 6;
  int wave = t >> 6;
  int lane = t & 63;
  int grp = lane & 15;
  int part = lane >> 4;
  int qbase = qt * 256 + wave * 64 + grp * 4;
  const size_t head_off = (size_t)b * SEQ * DIM + h * DK;

  float qreg[4][16];
#pragma unroll
  for (int r = 0; r < 4; r++) {
    const float* qp = q + head_off + (size_t)(qbase + r) * DIM + part * 16;
#pragma unroll
    for (int i = 0; i < 16; i += 4) {
      float4 qv = *(const float4*)(qp + i);
      qreg[r][i] = qv.x; qreg[r][i + 1] = qv.y;
      qreg[r][i + 2] = qv.z; qreg[r][i + 3] = qv.w;
    }
  }

  float o[4][16] = {};
  float mrun[4], lrun[4];
#pragma unroll
  for (int r = 0; r < 4; r++) { mrun[r] = -1e30f; lrun[r] = 0.f; }

  for (int kt = 0; kt < SEQ; kt += 64) {
    __syncthreads();
    // stage 64x64 K and V tiles: 1024 float4 each, 4 per thread
#pragma unroll
    for (int i = 0; i < 4; i++) {
      int id = i * 256 + t;
      int row = id >> 4;
      int c4 = (id & 15) * 4;
      *(float4*)(&Ks[row][c4]) =
          *(const float4*)(k + head_off + (size_t)(kt + row) * DIM + c4);
      *(float4*)(&Vs[row][c4]) =
          *(const float4*)(v + head_off + (size_t)(kt + row) * DIM + c4);
    }
    __syncthreads();

    for (int jj = 0; jj < 64; jj += 4) {
      float s[4][4];  // [kr][r]
#pragma unroll
      for (int kr = 0; kr < 4; kr++) {
        float kf[16];
#pragma unroll
        for (int i = 0; i < 16; i += 4) {
          float4 kv = *(const float4*)(&Ks[jj + kr][part * 16 + i]);
          kf[i] = kv.x; kf[i + 1] = kv.y; kf[i + 2] = kv.z; kf[i + 3] = kv.w;
        }
#pragma unroll
        for (int r = 0; r < 4; r++) {
          float p = 0.f;
#pragma unroll
          for (int i = 0; i < 16; i++) p += qreg[r][i] * kf[i];
          s[kr][r] = p;
        }
      }
      // butterfly across the 4 dim-parts, then scale by 1/sqrt(64)
#pragma unroll
      for (int kr = 0; kr < 4; kr++)
#pragma unroll
        for (int r = 0; r < 4; r++) {
          float p = s[kr][r];
          p += __shfl_xor(p, 16, 64);
          p += __shfl_xor(p, 32, 64);
          s[kr][r] = p * 0.125f;
        }
      // online softmax update (4 k-rows at once)
      float alpha[4];
#pragma unroll
      for (int r = 0; r < 4; r++) {
        float lm = fmaxf(fmaxf(s[0][r], s[1][r]), fmaxf(s[2][r], s[3][r]));
        float mnew = fmaxf(mrun[r], lm);
        alpha[r] = __expf(mrun[r] - mnew);
        mrun[r] = mnew;
        float wsum = 0.f;
#pragma unroll
        for (int kr = 0; kr < 4; kr++) {
          s[kr][r] = __expf(s[kr][r] - mnew);
          wsum += s[kr][r];
        }
        lrun[r] = lrun[r] * alpha[r] + wsum;
#pragma unroll
        for (int i = 0; i < 16; i++) o[r][i] *= alpha[r];
      }
#pragma unroll
      for (int kr = 0; kr < 4; kr++) {
        float vf[16];
#pragma unroll
        for (int i = 0; i < 16; i += 4) {
          float4 vv = *(const float4*)(&Vs[jj + kr][part * 16 + i]);
          vf[i] = vv.x; vf[i + 1] = vv.y; vf[i + 2] = vv.z; vf[i + 3] = vv.w;
        }
#pragma unroll
        for (int r = 0; r < 4; r++)
#pragma unroll
          for (int i = 0; i < 16; i++) o[r][i] += s[kr][r] * vf[i];
      }
    }
  }

#pragma unroll
  for (int r = 0; r < 4; r++) {
    float inv = 1.f / lrun[r];
    float* op = out + head_off + (size_t)(qbase + r) * DIM + part * 16;
#pragma unroll
    for (int i = 0; i < 16; i += 4) {
      float4 ov;
      ov.x = o[r][i] * inv; ov.y = o[r][i + 1] * inv;
      ov.z = o[r][i + 2] * inv; ov.w = o[r][i + 3] * inv;
      *(float4*)(op + i) = ov;
    }
  }
}

// ---------------------------------------------------------------------------
// Kernel 4: layernorm over last dim (512). One wave per row; 4 rows per block.
// ---------------------------------------------------------------------------
__global__ __launch_bounds__(256) void layernorm_kernel(
    const float* __restrict__ h, const float* __restrict__ g,
    const float* __restrict__ beta, float* __restrict__ out) {
  int wave = threadIdx.x >> 6;
  int lane = threadIdx.x & 63;
  int row = blockIdx.x * 4 + wave;
  const float* hp = h + (size_t)row * DIM + lane * 8;
  float vals[8];
  float4 v0 = *(const float4*)(hp);
  float4 v1 = *(const float4*)(hp + 4);
  vals[0] = v0.x; vals[1] = v0.y; vals[2] = v0.z; vals[3] = v0.w;
  vals[4] = v1.x; vals[5] = v1.y; vals[6] = v1.z; vals[7] = v1.w;
  float sum = 0.f;
#pragma unroll
  for (int i = 0; i < 8; i++) sum += vals[i];
#pragma unroll
  for (int off = 32; off >= 1; off >>= 1) sum += __shfl_xor(sum, off, 64);
  float mean = sum * (1.f / 512.f);
  float vs = 0.f;
#pragma unroll
  for (int i = 0; i < 8; i++) {
    float d = vals[i] - mean;
    vs += d * d;
  }
#pragma unroll
  for (int off = 32; off >= 1; off >>= 1) vs += __shfl_xor(vs, off, 64);
  float rstd = rsqrtf(vs * (1.f / 512.f) + 1e-5f);
  float4 gv0 = *(const float4*)(g + lane * 8);
  float4 gv1 = *(const float4*)(g + lane * 8 + 4);
  float4 bv0 = *(const float4*)(beta + lane * 8);
  float4 bv1 = *(const float4*)(beta + lane * 8 + 4);
  float gr[8] = {gv0.x, gv0.y, gv0.z, gv0.w, gv1.x, gv1.y, gv1.z, gv1.w};
  float br[8] = {bv0.x, bv0.y, bv0.z, bv0.w, bv1.x, bv1.y, bv1.z, bv1.w};
  float res[8];
#pragma unroll
  for (int i = 0; i < 8; i++) res[i] = (vals[i] - mean) * rstd * gr[i] + br[i];
  float* op = out + (size_t)row * DIM + lane * 8;
  float4 o0, o1;
  o0.x = res[0]; o0.y = res[1]; o0.z = res[2]; o0.w = res[3];
  o1.x = res[4]; o1.y = res[5]; o1.z = res[6]; o1.w = res[7];
  *(float4*)(op) = o0;
  *(float4*)(op + 4) = o1;
}

// ---------------------------------------------------------------------------
extern "C" void kernel_launch(void* const* d_in, const int* in_sizes, int n_in,
                              void* d_out, int out_size, void* d_ws,
                              size_t ws_size, hipStream_t stream) {
  (void)in_sizes; (void)n_in; (void)out_size; (void)ws_size;
  const float* x     = (const float*)d_in[0];
  const float* vis   = (const float*)d_in[1];
  const int*   c1    = (const int*)d_in[2];
  const int*   c2    = (const int*)d_in[3];
  const float* e1    = (const float*)d_in[4];
  const float* e2    = (const float*)d_in[5];
  const float* wq    = (const float*)d_in[6];
  const float* bq    = (const float*)d_in[7];
  const float* wk    = (const float*)d_in[8];
  const float* bk    = (const float*)d_in[9];
  const float* wv    = (const float*)d_in[10];
  const float* bv    = (const float*)d_in[11];
  const float* w1    = (const float*)d_in[12];
  const float* b1    = (const float*)d_in[13];
  const float* g1    = (const float*)d_in[14];
  const float* beta1 = (const float*)d_in[15];
  const float* w2    = (const float*)d_in[16];
  const float* b2    = (const float*)d_in[17];
  const float* g2    = (const float*)d_in[18];
  const float* beta2 = (const float*)d_in[19];
  float* out = (float*)d_out;
  float* ws = (float*)d_ws;

  const size_t BUF = (size_t)MROWS * DIM;  // 4,194,304 floats = 16 MB
  float* xp = ws;            // xp, later reused as attn_out
  float* qb = ws + BUF;      // q, later h1
  float* kb = ws + 2 * BUF;  // k, later h2
  float* vb = ws + 3 * BUF;  // v

  dim3 ggrid(8, 128);  // N/64, M/64

  pos_add_kernel<<<4096, 256, 0, stream>>>(x, c1, c2, e1, e2, xp);
  gemm_bias_kernel<false><<<ggrid, 256, 0, stream>>>(vis, wq, bq, qb);
  gemm_bias_kernel<false><<<ggrid, 256, 0, stream>>>(vis, wk, bk, kb);
  gemm_bias_kernel<false><<<ggrid, 256, 0, stream>>>(xp, wv, bv, vb);
  attn_kernel<<<256, 256, 0, stream>>>(qb, kb, vb, xp);  // attn_out -> xp
  gemm_bias_kernel<true><<<ggrid, 256, 0, stream>>>(xp, w1, b1, qb);   // h1
  layernorm_kernel<<<2048, 256, 0, stream>>>(qb, g1, beta1, qb);       // in-place
  gemm_bias_kernel<true><<<ggrid, 256, 0, stream>>>(qb, w2, b2, kb);   // h2
  layernorm_kernel<<<2048, 256, 0, stream>>>(kb, g2, beta2, out);
}

// Round 2
// 358.126 us; speedup vs baseline: 4.9316x; 4.9316x over previous
//
#include <hip/hip_runtime.h>

#define DIM 512
#define SEQ 2048
#define MROWS 8192

typedef short short8 __attribute__((ext_vector_type(8)));
typedef float floatx4 __attribute__((ext_vector_type(4)));

__device__ __forceinline__ ushort f2bf(float f) {
  union { float f; unsigned u; } v; v.f = f;
  unsigned r = v.u + 0x7fff + ((v.u >> 16) & 1);
  return (ushort)(r >> 16);
}
__device__ __forceinline__ float bf2f(ushort u) {
  union { unsigned u; float f; } v; v.u = ((unsigned)u) << 16;
  return v.f;
}

// ---------------------------------------------------------------------------
// prep: vis -> bf16; xp = x + concat(emb1[c1], emb2[c2]) -> bf16
// ---------------------------------------------------------------------------
__global__ __launch_bounds__(256) void prep_kernel(
    const float* __restrict__ x, const float* __restrict__ vis,
    const int* __restrict__ c1, const int* __restrict__ c2,
    const float* __restrict__ e1, const float* __restrict__ e2,
    ushort* __restrict__ xp_bf, ushort* __restrict__ vis_bf) {
  int gid = blockIdx.x * 256 + threadIdx.x;
  int row = gid >> 7;
  int col = (gid & 127) * 4;
  float4 vv = *(const float4*)(vis + (size_t)row * 512 + col);
  ushort4 vb; vb.x = f2bf(vv.x); vb.y = f2bf(vv.y); vb.z = f2bf(vv.z); vb.w = f2bf(vv.w);
  *(ushort4*)(vis_bf + (size_t)row * 512 + col) = vb;
  float4 p;
  if (col < 256) p = *(const float4*)(e1 + (size_t)c1[row] * 256 + col);
  else           p = *(const float4*)(e2 + (size_t)c2[row] * 256 + col - 256);
  float4 xv = *(const float4*)(x + (size_t)row * 512 + col);
  ushort4 xb; xb.x = f2bf(xv.x + p.x); xb.y = f2bf(xv.y + p.y);
  xb.z = f2bf(xv.z + p.z); xb.w = f2bf(xv.w + p.w);
  *(ushort4*)(xp_bf + (size_t)row * 512 + col) = xb;
}

// ---------------------------------------------------------------------------
// weight transpose+convert: Wt[n][k] = W[k][n] (bf16). mid 0 (wq) pre-scaled
// by softmax 1/sqrt(64)=0.125 (exact fold into Q).
// grid = 5 matrices * 32 n-chunks = 160 blocks, 256 threads.
// ---------------------------------------------------------------------------
__global__ __launch_bounds__(256) void wtrans_kernel(
    const float* __restrict__ wq, const float* __restrict__ wk,
    const float* __restrict__ wv, const float* __restrict__ w1,
    const float* __restrict__ w2,
    ushort* __restrict__ wt_qkv, ushort* __restrict__ wt1,
    ushort* __restrict__ wt2) {
  int mid = blockIdx.x >> 5;
  int n0 = (blockIdx.x & 31) * 16;
  const float* W = mid == 0 ? wq : mid == 1 ? wk : mid == 2 ? wv : mid == 3 ? w1 : w2;
  ushort* out = mid < 3 ? (wt_qkv + (size_t)mid * 512 * 512) : (mid == 3 ? wt1 : wt2);
  float scale = (mid == 0) ? 0.125f : 1.0f;
  int kk = threadIdx.x * 2;
#pragma unroll 4
  for (int n = 0; n < 16; n++) {
    float a = W[(size_t)kk * 512 + n0 + n] * scale;
    float b = W[(size_t)(kk + 1) * 512 + n0 + n] * scale;
    unsigned pack = (unsigned)f2bf(a) | ((unsigned)f2bf(b) << 16);
    *(unsigned*)(out + (size_t)(n0 + n) * 512 + kk) = pack;
  }
}

// ---------------------------------------------------------------------------
// bf16 MFMA GEMM: C[m][nloc] = A[m][:] @ W[:, n] + bias (+leaky), out bf16.
// Tile 128x128, BK=64, 4 waves in 2x2, wave tile 64x64 (4x4 of 16x16).
// Wt is pre-transposed: row n holds W[:,n]. blockIdx.x covers global n in
// 128-chunks; segment = n>>9 selects {A, bias, out} (QKV fusion). For plain
// GEMMs grid.x=4 so seg==0 always.
// ---------------------------------------------------------------------------
template <bool LEAKY>
__global__ __launch_bounds__(256, 3) void gemm_mfma(
    const ushort* __restrict__ A01, const ushort* __restrict__ A2,
    const ushort* __restrict__ Wt,
    const float* __restrict__ bias0, const float* __restrict__ bias1,
    const float* __restrict__ bias2,
    ushort* __restrict__ out0, ushort* __restrict__ out1,
    ushort* __restrict__ out2, float s0scale) {
  __shared__ __align__(16) ushort As[128 * 64];
  __shared__ __align__(16) ushort Bs[128 * 64];
  int t = threadIdx.x;
  int seg = blockIdx.x >> 2;
  int nloc0 = (blockIdx.x & 3) * 128;
  int n0w = blockIdx.x * 128;
  int m0 = blockIdx.y * 128;
  const ushort* A = (seg < 2) ? A01 : A2;
  const float* bias = seg == 0 ? bias0 : seg == 1 ? bias1 : bias2;
  ushort* out = seg == 0 ? out0 : seg == 1 ? out1 : out2;
  float bscale = seg == 0 ? s0scale : 1.0f;

  int w = t >> 6, lane = t & 63;
  int wm = (w & 1) * 64, wn = (w >> 1) * 64;
  int quad = lane >> 4, lcol = lane & 15;
  int srow = t >> 3, sch = t & 7;

  floatx4 acc[4][4] = {};

  for (int k0 = 0; k0 < 512; k0 += 64) {
    __syncthreads();
#pragma unroll
    for (int i = 0; i < 4; i++) {
      int row = i * 32 + srow;
      *(uint4*)(&As[row * 64 + sch * 8]) =
          *(const uint4*)(A + (size_t)(m0 + row) * 512 + k0 + sch * 8);
      *(uint4*)(&Bs[row * 64 + sch * 8]) =
          *(const uint4*)(Wt + (size_t)(n0w + row) * 512 + k0 + sch * 8);
    }
    __syncthreads();
#pragma unroll
    for (int kc = 0; kc < 2; kc++) {
      short8 af[4], bfr[4];
#pragma unroll
      for (int i = 0; i < 4; i++) {
        af[i] = *(const short8*)(&As[(wm + i * 16 + lcol) * 64 + kc * 32 + quad * 8]);
        bfr[i] = *(const short8*)(&Bs[(wn + i * 16 + lcol) * 64 + kc * 32 + quad * 8]);
      }
#pragma unroll
      for (int mt = 0; mt < 4; mt++)
#pragma unroll
        for (int nt = 0; nt < 4; nt++)
          acc[mt][nt] = __builtin_amdgcn_mfma_f32_16x16x32_bf16(
              af[mt], bfr[nt], acc[mt][nt], 0, 0, 0);
    }
  }

#pragma unroll
  for (int nt = 0; nt < 4; nt++) {
    int ncol = nloc0 + wn + nt * 16 + lcol;
    float bv = bias[ncol] * bscale;
#pragma unroll
    for (int mt = 0; mt < 4; mt++) {
#pragma unroll
      for (int r = 0; r < 4; r++) {
        float vv = acc[mt][nt][r] + bv;
        if (LEAKY) vv = vv >= 0.f ? vv : 0.2f * vv;
        out[(size_t)(m0 + wm + mt * 16 + quad * 4 + r) * 512 + ncol] = f2bf(vv);
      }
    }
  }
}

// ---------------------------------------------------------------------------
// MFMA flash attention. q,k,v,out bf16 [B,S,512] viewed as [B,S,8,64].
// Q pre-scaled by 0.125 (folded into wq). Block = (b,h,64 q-rows), 4 waves
// of 16 q-rows. K-tile 64x64 in Ks[j][d] (stride 72), V-tile transposed in
// Vt[d][j], P round-trips via wave-private LDS (stride 72).
// ---------------------------------------------------------------------------
__global__ __launch_bounds__(256, 4) void attn_mfma_kernel(
    const ushort* __restrict__ q, const ushort* __restrict__ k,
    const ushort* __restrict__ v, ushort* __restrict__ out) {
  __shared__ __align__(16) ushort Ks[64 * 72];
  __shared__ __align__(16) ushort Vt[64 * 72];
  __shared__ __align__(16) ushort Ps[4 * 16 * 72];
  int t = threadIdx.x;
  int blk = blockIdx.x;
  int qt = blk & 31, h = (blk >> 5) & 7, b = blk >> 8;
  int wave = t >> 6, lane = t & 63, quad = lane >> 4, lcol = lane & 15;
  int q0 = qt * 64 + wave * 16;
  const size_t base = (size_t)b * SEQ * 512 + h * 64;

  short8 qf[2];
#pragma unroll
  for (int kc = 0; kc < 2; kc++)
    qf[kc] = *(const short8*)(q + base + (size_t)(q0 + lcol) * 512 + kc * 32 + quad * 8);

  floatx4 O[4] = {};
  float mrun[4], lrun[4];
#pragma unroll
  for (int r = 0; r < 4; r++) { mrun[r] = -1e30f; lrun[r] = 0.f; }

  ushort* Pw = Ps + wave * 16 * 72;
  int krow = t >> 3, kch = t & 7;
  int jp = t & 31, dc = t >> 5;

  for (int kt = 0; kt < SEQ; kt += 64) {
    __syncthreads();
#pragma unroll
    for (int i = 0; i < 2; i++) {
      int row = i * 32 + krow;
      *(uint4*)(&Ks[row * 72 + kch * 8]) =
          *(const uint4*)(k + base + (size_t)(kt + row) * 512 + kch * 8);
    }
    {
      uint4 v0 = *(const uint4*)(v + base + (size_t)(kt + jp * 2) * 512 + dc * 8);
      uint4 v1 = *(const uint4*)(v + base + (size_t)(kt + jp * 2 + 1) * 512 + dc * 8);
      const ushort* a0 = (const ushort*)&v0;
      const ushort* a1 = (const ushort*)&v1;
#pragma unroll
      for (int i = 0; i < 8; i++) {
        unsigned pack = (unsigned)a0[i] | ((unsigned)a1[i] << 16);
        *(unsigned*)(&Vt[(dc * 8 + i) * 72 + jp * 2]) = pack;
      }
    }
    __syncthreads();

    // QK^T -> S (C-layout: row=quad*4+r is q-row, col=jt*16+lcol is k-col)
    floatx4 S[4] = {};
#pragma unroll
    for (int kc = 0; kc < 2; kc++) {
#pragma unroll
      for (int jt = 0; jt < 4; jt++) {
        short8 kf = *(const short8*)(&Ks[(jt * 16 + lcol) * 72 + kc * 32 + quad * 8]);
        S[jt] = __builtin_amdgcn_mfma_f32_16x16x32_bf16(qf[kc], kf, S[jt], 0, 0, 0);
      }
    }

    // online softmax
    float alpha[4];
#pragma unroll
    for (int r = 0; r < 4; r++) {
      float mx = fmaxf(fmaxf(S[0][r], S[1][r]), fmaxf(S[2][r], S[3][r]));
#pragma unroll
      for (int m = 1; m <= 8; m <<= 1) mx = fmaxf(mx, __shfl_xor(mx, m, 64));
      float mnew = fmaxf(mrun[r], mx);
      alpha[r] = __expf(mrun[r] - mnew);
      mrun[r] = mnew;
      float ls = 0.f;
#pragma unroll
      for (int jt = 0; jt < 4; jt++) {
        float p = __expf(S[jt][r] - mnew);
        S[jt][r] = p;
        ls += p;
      }
#pragma unroll
      for (int m = 1; m <= 8; m <<= 1) ls += __shfl_xor(ls, m, 64);
      lrun[r] = lrun[r] * alpha[r] + ls;
    }

    // write P (bf16) to wave-private LDS; rescale O
#pragma unroll
    for (int jt = 0; jt < 4; jt++)
#pragma unroll
      for (int r = 0; r < 4; r++)
        Pw[(quad * 4 + r) * 72 + jt * 16 + lcol] = f2bf(S[jt][r]);
#pragma unroll
    for (int nt = 0; nt < 4; nt++)
#pragma unroll
      for (int r = 0; r < 4; r++) O[nt][r] *= alpha[r];
    asm volatile("s_waitcnt lgkmcnt(0)" ::: "memory");

    // PV: O[i][d] += P[i][j] * V[j][d]   (A=P rows, B=Vt rows, both b128)
#pragma unroll
    for (int kc = 0; kc < 2; kc++) {
      short8 pf = *(const short8*)(&Pw[lcol * 72 + kc * 32 + quad * 8]);
#pragma unroll
      for (int nt = 0; nt < 4; nt++) {
        short8 vf = *(const short8*)(&Vt[(nt * 16 + lcol) * 72 + kc * 32 + quad * 8]);
        O[nt] = __builtin_amdgcn_mfma_f32_16x16x32_bf16(pf, vf, O[nt], 0, 0, 0);
      }
    }
  }

#pragma unroll
  for (int r = 0; r < 4; r++) lrun[r] = 1.f / lrun[r];
#pragma unroll
  for (int nt = 0; nt < 4; nt++)
#pragma unroll
    for (int r = 0; r < 4; r++)
      out[base + (size_t)(q0 + quad * 4 + r) * 512 + nt * 16 + lcol] =
          f2bf(O[nt][r] * lrun[r]);
}

// ---------------------------------------------------------------------------
// layernorm over last dim (512), bf16 in; bf16 or fp32 out.
// ---------------------------------------------------------------------------
template <bool OUTF32>
__global__ __launch_bounds__(256) void ln_kernel(
    const ushort* __restrict__ h, const float* __restrict__ g,
    const float* __restrict__ beta, void* __restrict__ outv) {
  int wave = threadIdx.x >> 6, lane = threadIdx.x & 63;
  int row = blockIdx.x * 4 + wave;
  uint4 raw = *(const uint4*)(h + (size_t)row * 512 + lane * 8);
  const ushort* hu = (const ushort*)&raw;
  float vals[8];
#pragma unroll
  for (int i = 0; i < 8; i++) vals[i] = bf2f(hu[i]);
  float sum = 0.f;
#pragma unroll
  for (int i = 0; i < 8; i++) sum += vals[i];
#pragma unroll
  for (int off = 32; off >= 1; off >>= 1) sum += __shfl_xor(sum, off, 64);
  float mean = sum * (1.f / 512.f);
  float vs = 0.f;
#pragma unroll
  for (int i = 0; i < 8; i++) { float d = vals[i] - mean; vs += d * d; }
#pragma unroll
  for (int off = 32; off >= 1; off >>= 1) vs += __shfl_xor(vs, off, 64);
  float rstd = rsqrtf(vs * (1.f / 512.f) + 1e-5f);
  float4 gv0 = *(const float4*)(g + lane * 8);
  float4 gv1 = *(const float4*)(g + lane * 8 + 4);
  float4 bv0 = *(const float4*)(beta + lane * 8);
  float4 bv1 = *(const float4*)(beta + lane * 8 + 4);
  float gr[8] = {gv0.x, gv0.y, gv0.z, gv0.w, gv1.x, gv1.y, gv1.z, gv1.w};
  float br[8] = {bv0.x, bv0.y, bv0.z, bv0.w, bv1.x, bv1.y, bv1.z, bv1.w};
  float res[8];
#pragma unroll
  for (int i = 0; i < 8; i++) res[i] = (vals[i] - mean) * rstd * gr[i] + br[i];
  if (OUTF32) {
    float* op = (float*)outv + (size_t)row * 512 + lane * 8;
    float4 o0, o1;
    o0.x = res[0]; o0.y = res[1]; o0.z = res[2]; o0.w = res[3];
    o1.x = res[4]; o1.y = res[5]; o1.z = res[6]; o1.w = res[7];
    *(float4*)op = o0; *(float4*)(op + 4) = o1;
  } else {
    ushort* op = (ushort*)outv + (size_t)row * 512 + lane * 8;
    ushort4 o0, o1;
    o0.x = f2bf(res[0]); o0.y = f2bf(res[1]); o0.z = f2bf(res[2]); o0.w = f2bf(res[3]);
    o1.x = f2bf(res[4]); o1.y = f2bf(res[5]); o1.z = f2bf(res[6]); o1.w = f2bf(res[7]);
    *(ushort4*)op = o0; *(ushort4*)(op + 4) = o1;
  }
}

// ---------------------------------------------------------------------------
extern "C" void kernel_launch(void* const* d_in, const int* in_sizes, int n_in,
                              void* d_out, int out_size, void* d_ws,
                              size_t ws_size, hipStream_t stream) {
  (void)in_sizes; (void)n_in; (void)out_size; (void)ws_size;
  const float* x     = (const float*)d_in[0];
  const float* vis   = (const float*)d_in[1];
  const int*   c1    = (const int*)d_in[2];
  const int*   c2    = (const int*)d_in[3];
  const float* e1    = (const float*)d_in[4];
  const float* e2    = (const float*)d_in[5];
  const float* wq    = (const float*)d_in[6];
  const float* bq    = (const float*)d_in[7];
  const float* wk    = (const float*)d_in[8];
  const float* bk    = (const float*)d_in[9];
  const float* wv    = (const float*)d_in[10];
  const float* bv    = (const float*)d_in[11];
  const float* w1    = (const float*)d_in[12];
  const float* b1    = (const float*)d_in[13];
  const float* g1    = (const float*)d_in[14];
  const float* beta1 = (const float*)d_in[15];
  const float* w2    = (const float*)d_in[16];
  const float* b2    = (const float*)d_in[17];
  const float* g2    = (const float*)d_in[18];
  const float* beta2 = (const float*)d_in[19];
  float* out = (float*)d_out;
  ushort* ws = (ushort*)d_ws;

  const size_t BUF = (size_t)MROWS * 512;  // 4,194,304 elements
  ushort* xp_bf  = ws;             // later reused as h1
  ushort* vis_bf = ws + BUF;       // later reused as attn_out
  ushort* q_bf   = ws + 2 * BUF;   // later reused as ln1
  ushort* k_bf   = ws + 3 * BUF;   // later reused as h2
  ushort* v_bf   = ws + 4 * BUF;
  ushort* wt_qkv = ws + 5 * BUF;              // 1536*512
  ushort* wt1    = wt_qkv + 1536 * 512;       // 512*512
  ushort* wt2    = wt1 + 512 * 512;           // 512*512
  ushort* attn_bf = vis_bf;
  ushort* h1_bf   = xp_bf;
  ushort* ln1_bf  = q_bf;
  ushort* h2_bf   = k_bf;

  prep_kernel<<<4096, 256, 0, stream>>>(x, vis, c1, c2, e1, e2, xp_bf, vis_bf);
  wtrans_kernel<<<160, 256, 0, stream>>>(wq, wk, wv, w1, w2, wt_qkv, wt1, wt2);
  // fused QKV: N=1536 (q|k|v), A = vis for q/k, xp for v; wq pre-scaled 0.125
  gemm_mfma<false><<<dim3(12, 64), 256, 0, stream>>>(
      vis_bf, xp_bf, wt_qkv, bq, bk, bv, q_bf, k_bf, v_bf, 0.125f);
  attn_mfma_kernel<<<1024, 256, 0, stream>>>(q_bf, k_bf, v_bf, attn_bf);
  gemm_mfma<true><<<dim3(4, 64), 256, 0, stream>>>(
      attn_bf, attn_bf, wt1, b1, b1, b1, h1_bf, h1_bf, h1_bf, 1.0f);
  ln_kernel<false><<<2048, 256, 0, stream>>>(h1_bf, g1, beta1, ln1_bf);
  gemm_mfma<true><<<dim3(4, 64), 256, 0, stream>>>(
      ln1_bf, ln1_bf, wt2, b2, b2, b2, h2_bf, h2_bf, h2_bf, 1.0f);
  ln_kernel<true><<<2048, 256, 0, stream>>>(h2_bf, g2, beta2, out);
}

// Round 3
// 308.099 us; speedup vs baseline: 5.7324x; 1.1624x over previous
//
#include <hip/hip_runtime.h>

#define DIM 512
#define SEQ 2048
#define MROWS 8192

typedef short short8 __attribute__((ext_vector_type(8)));
typedef float floatx4 __attribute__((ext_vector_type(4)));

__device__ __forceinline__ ushort f2bf(float f) {
  union { float f; unsigned u; } v; v.f = f;
  unsigned r = v.u + 0x7fff + ((v.u >> 16) & 1);
  return (ushort)(r >> 16);
}
__device__ __forceinline__ float bf2f(ushort u) {
  union { unsigned u; float f; } v; v.u = ((unsigned)u) << 16;
  return v.f;
}

// ---------------------------------------------------------------------------
// prep: vis -> bf16; xp = x + concat(emb1[c1], emb2[c2]) -> bf16
// ---------------------------------------------------------------------------
__global__ __launch_bounds__(256) void prep_kernel(
    const float* __restrict__ x, const float* __restrict__ vis,
    const int* __restrict__ c1, const int* __restrict__ c2,
    const float* __restrict__ e1, const float* __restrict__ e2,
    ushort* __restrict__ xp_bf, ushort* __restrict__ vis_bf) {
  int gid = blockIdx.x * 256 + threadIdx.x;
  int row = gid >> 7;
  int col = (gid & 127) * 4;
  float4 vv = *(const float4*)(vis + (size_t)row * 512 + col);
  ushort4 vb; vb.x = f2bf(vv.x); vb.y = f2bf(vv.y); vb.z = f2bf(vv.z); vb.w = f2bf(vv.w);
  *(ushort4*)(vis_bf + (size_t)row * 512 + col) = vb;
  float4 p;
  if (col < 256) p = *(const float4*)(e1 + (size_t)c1[row] * 256 + col);
  else           p = *(const float4*)(e2 + (size_t)c2[row] * 256 + col - 256);
  float4 xv = *(const float4*)(x + (size_t)row * 512 + col);
  ushort4 xb; xb.x = f2bf(xv.x + p.x); xb.y = f2bf(xv.y + p.y);
  xb.z = f2bf(xv.z + p.z); xb.w = f2bf(xv.w + p.w);
  *(ushort4*)(xp_bf + (size_t)row * 512 + col) = xb;
}

// ---------------------------------------------------------------------------
// weight transpose+convert, coalesced via LDS 64x64 tile.
// Wt[n][k] = W[k][n] (bf16); mid 0 (wq) pre-scaled by 0.125.
// grid = 5 * 64 tiles, 256 threads.
// ---------------------------------------------------------------------------
__global__ __launch_bounds__(256) void wtrans_kernel(
    const float* __restrict__ wq, const float* __restrict__ wk,
    const float* __restrict__ wv, const float* __restrict__ w1,
    const float* __restrict__ w2,
    ushort* __restrict__ wt_qkv, ushort* __restrict__ wt1,
    ushort* __restrict__ wt2) {
  __shared__ float Ls[64 * 65];
  int mid = blockIdx.x >> 6;
  int tile = blockIdx.x & 63;
  int k0 = (tile >> 3) * 64, n0 = (tile & 7) * 64;
  const float* W = mid == 0 ? wq : mid == 1 ? wk : mid == 2 ? wv : mid == 3 ? w1 : w2;
  ushort* outp = mid < 3 ? (wt_qkv + (size_t)mid * 512 * 512) : (mid == 3 ? wt1 : wt2);
  float scale = (mid == 0) ? 0.125f : 1.0f;
  int r = threadIdx.x >> 4, c4 = (threadIdx.x & 15) * 4;
#pragma unroll
  for (int i = 0; i < 4; i++) {
    int row = i * 16 + r;
    float4 wv4 = *(const float4*)(W + (size_t)(k0 + row) * 512 + n0 + c4);
    Ls[row * 65 + c4 + 0] = wv4.x * scale;
    Ls[row * 65 + c4 + 1] = wv4.y * scale;
    Ls[row * 65 + c4 + 2] = wv4.z * scale;
    Ls[row * 65 + c4 + 3] = wv4.w * scale;
  }
  __syncthreads();
  int n = threadIdx.x >> 2, kc = (threadIdx.x & 3) * 16;
  ushort pk[16];
#pragma unroll
  for (int i = 0; i < 16; i++) pk[i] = f2bf(Ls[(kc + i) * 65 + n]);
  ushort* op = outp + (size_t)(n0 + n) * 512 + k0 + kc;
  *(uint4*)op = *(uint4*)pk;
  *(uint4*)(op + 8) = *(uint4*)(pk + 8);
}

// ---------------------------------------------------------------------------
// bf16 MFMA GEMM, 128x128 tile, BK=64, XOR-swizzled LDS (chunk ^= row&7),
// LDS-transposed epilogue with dwordx4 stores. QKV fusion via seg select.
// ---------------------------------------------------------------------------
template <bool LEAKY>
__global__ __launch_bounds__(256, 3) void gemm_mfma(
    const ushort* __restrict__ A01, const ushort* __restrict__ A2,
    const ushort* __restrict__ Wt,
    const float* __restrict__ bias0, const float* __restrict__ bias1,
    const float* __restrict__ bias2,
    ushort* __restrict__ out0, ushort* __restrict__ out1,
    ushort* __restrict__ out2, float s0scale) {
  __shared__ __align__(16) ushort As[128 * 64];
  __shared__ __align__(16) ushort Bs[128 * 64];
  int t = threadIdx.x;
  int seg = blockIdx.x >> 2;
  int nloc0 = (blockIdx.x & 3) * 128;
  int n0w = blockIdx.x * 128;
  int m0 = blockIdx.y * 128;
  const ushort* A = (seg < 2) ? A01 : A2;
  const float* bias = seg == 0 ? bias0 : seg == 1 ? bias1 : bias2;
  ushort* out = seg == 0 ? out0 : seg == 1 ? out1 : out2;
  float bscale = seg == 0 ? s0scale : 1.0f;

  int w = t >> 6, lane = t & 63;
  int wm = (w & 1) * 64, wn = (w >> 1) * 64;
  int quad = lane >> 4, lcol = lane & 15;
  int srow = t >> 3, sch = t & 7;

  floatx4 acc[4][4] = {};

  for (int k0 = 0; k0 < 512; k0 += 64) {
    __syncthreads();
#pragma unroll
    for (int i = 0; i < 4; i++) {
      int row = i * 32 + srow;
      int pofs = row * 64 + (sch ^ (row & 7)) * 8;
      *(uint4*)(&As[pofs]) =
          *(const uint4*)(A + (size_t)(m0 + row) * 512 + k0 + sch * 8);
      *(uint4*)(&Bs[pofs]) =
          *(const uint4*)(Wt + (size_t)(n0w + row) * 512 + k0 + sch * 8);
    }
    __syncthreads();
#pragma unroll
    for (int kc = 0; kc < 2; kc++) {
      int pch = ((kc * 4 + quad) ^ (lcol & 7)) * 8;
      short8 af[4], bfr[4];
#pragma unroll
      for (int i = 0; i < 4; i++) {
        af[i]  = *(const short8*)(&As[(wm + i * 16 + lcol) * 64 + pch]);
        bfr[i] = *(const short8*)(&Bs[(wn + i * 16 + lcol) * 64 + pch]);
      }
#pragma unroll
      for (int mt = 0; mt < 4; mt++)
#pragma unroll
        for (int nt = 0; nt < 4; nt++)
          acc[mt][nt] = __builtin_amdgcn_mfma_f32_16x16x32_bf16(
              af[mt], bfr[nt], acc[mt][nt], 0, 0, 0);
    }
  }

  // epilogue: wave-private LDS transpose -> coalesced 16B stores
  __syncthreads();
  float* Ls = ((w & 2) ? (float*)Bs : (float*)As) + (w & 1) * 1104;
  int rr = lane >> 2, cc = (lane & 3) * 16;
#pragma unroll
  for (int mt = 0; mt < 4; mt++) {
#pragma unroll
    for (int nt = 0; nt < 4; nt++) {
      float bv = bias[nloc0 + wn + nt * 16 + lcol] * bscale;
#pragma unroll
      for (int r = 0; r < 4; r++) {
        float vv = acc[mt][nt][r] + bv;
        if (LEAKY) vv = vv >= 0.f ? vv : 0.2f * vv;
        Ls[(quad * 4 + r) * 68 + nt * 16 + lcol] = vv;
      }
    }
    asm volatile("s_waitcnt lgkmcnt(0)" ::: "memory");
    ushort pk[16];
#pragma unroll
    for (int i = 0; i < 16; i += 4) {
      float4 fv = *(const float4*)(&Ls[rr * 68 + cc + i]);
      pk[i] = f2bf(fv.x); pk[i + 1] = f2bf(fv.y);
      pk[i + 2] = f2bf(fv.z); pk[i + 3] = f2bf(fv.w);
    }
    ushort* op = out + (size_t)(m0 + wm + mt * 16 + rr) * 512 + nloc0 + wn + cc;
    *(uint4*)op = *(uint4*)pk;
    *(uint4*)(op + 8) = *(uint4*)(pk + 8);
    asm volatile("s_waitcnt lgkmcnt(0)" ::: "memory");
  }
}

// ---------------------------------------------------------------------------
// MFMA flash attention, static-max softmax (scores bounded; exp in f32 is
// safe), K-tile=128, swizzled LDS, no per-tile cross-lane reduces.
// Block = (b,h,64 q-rows), 4 waves x 16 q-rows. 1024 blocks, 4/CU.
// ---------------------------------------------------------------------------
__global__ __launch_bounds__(256, 4) void attn_mfma_kernel(
    const ushort* __restrict__ q, const ushort* __restrict__ k,
    const ushort* __restrict__ v, ushort* __restrict__ out) {
  __shared__ __align__(16) ushort Ks[128 * 64];  // [krow][dim], swizzled
  __shared__ __align__(16) ushort Vt[64 * 128];  // [dim][krow], swizzled
  __shared__ __align__(16) ushort Ps[4 * 16 * 64];  // wave-private P halves
  int t = threadIdx.x;
  int blk = blockIdx.x;
  int qt = blk & 31, h = (blk >> 5) & 7, b = blk >> 8;
  int wave = t >> 6, lane = t & 63, quad = lane >> 4, lcol = lane & 15;
  int q0 = qt * 64 + wave * 16;
  const size_t base = (size_t)b * SEQ * 512 + h * 64;

  short8 qf[2];
#pragma unroll
  for (int kc = 0; kc < 2; kc++)
    qf[kc] = *(const short8*)(q + base + (size_t)(q0 + lcol) * 512 + kc * 32 + quad * 8);

  floatx4 O[4] = {};
  float lsum[4] = {0.f, 0.f, 0.f, 0.f};

  ushort* Pw = Ps + wave * (16 * 64);
  int krow = t >> 1, khalf = t & 1;   // K staging: 2 threads/row
  int pl = t & 63, dg = t >> 6;       // V staging: row-pair pl, dim group dg

  for (int kt = 0; kt < SEQ; kt += 128) {
    __syncthreads();
    // stage K: 128 rows x 64 dims, swizzled chunks
#pragma unroll
    for (int j = 0; j < 4; j++) {
      int ch = khalf * 4 + j;
      *(uint4*)(&Ks[krow * 64 + (ch ^ (krow & 7)) * 8]) =
          *(const uint4*)(k + base + (size_t)(kt + krow) * 512 + ch * 8);
    }
    // stage V transposed: Vt[dim][krow]
    {
      uint4 va[2], vb[2];
      const ushort* vr0 = v + base + (size_t)(kt + 2 * pl) * 512 + dg * 16;
      const ushort* vr1 = vr0 + 512;
      va[0] = *(const uint4*)(vr0); va[1] = *(const uint4*)(vr0 + 8);
      vb[0] = *(const uint4*)(vr1); vb[1] = *(const uint4*)(vr1 + 8);
      const ushort* a0 = (const ushort*)va;
      const ushort* a1 = (const ushort*)vb;
#pragma unroll
      for (int i = 0; i < 16; i++) {
        int dim = dg * 16 + i;
        unsigned pack = (unsigned)a0[i] | ((unsigned)a1[i] << 16);
        int pch = (pl >> 2) ^ (dim & 7);
        *(unsigned*)(&Vt[dim * 128 + pch * 8 + (pl & 3) * 2]) = pack;
      }
    }
    __syncthreads();

    // QK^T over 128 k-cols
    floatx4 S[8] = {};
#pragma unroll
    for (int kc = 0; kc < 2; kc++) {
      int pch = ((kc * 4 + quad) ^ (lcol & 7)) * 8;
#pragma unroll
      for (int jt = 0; jt < 8; jt++) {
        short8 kf = *(const short8*)(&Ks[(jt * 16 + lcol) * 64 + pch]);
        S[jt] = __builtin_amdgcn_mfma_f32_16x16x32_bf16(qf[kc], kf, S[jt], 0, 0, 0);
      }
    }

    // exp (no max subtraction), accumulate l, P -> LDS (trunc bf16), PV
#pragma unroll
    for (int half = 0; half < 2; half++) {
#pragma unroll
      for (int jt4 = 0; jt4 < 4; jt4++) {
        int jt = half * 4 + jt4;
#pragma unroll
        for (int r = 0; r < 4; r++) {
          float p = __expf(S[jt][r]);
          lsum[r] += p;
          int prow = quad * 4 + r;
          int pcol = jt4 * 16 + lcol;
          int pch = (pcol >> 3) ^ (prow & 7);
          Pw[prow * 64 + pch * 8 + (pcol & 7)] =
              (ushort)(__float_as_uint(p) >> 16);
        }
      }
      asm volatile("s_waitcnt lgkmcnt(0)" ::: "memory");
#pragma unroll
      for (int kc = 0; kc < 2; kc++) {
        short8 pf = *(const short8*)(
            &Pw[lcol * 64 + ((kc * 4 + quad) ^ (lcol & 7)) * 8]);
#pragma unroll
        for (int nt = 0; nt < 4; nt++) {
          int dim = nt * 16 + lcol;
          int ch = half * 8 + kc * 4 + quad;
          short8 vf = *(const short8*)(&Vt[dim * 128 + (ch ^ (lcol & 7)) * 8]);
          O[nt] = __builtin_amdgcn_mfma_f32_16x16x32_bf16(pf, vf, O[nt], 0, 0, 0);
        }
      }
    }
  }

  // final: reduce l across the 16 lanes holding each row, normalize, store
#pragma unroll
  for (int r = 0; r < 4; r++) {
#pragma unroll
    for (int m = 1; m <= 8; m <<= 1) lsum[r] += __shfl_xor(lsum[r], m, 64);
    lsum[r] = 1.f / lsum[r];
  }
#pragma unroll
  for (int nt = 0; nt < 4; nt++)
#pragma unroll
    for (int r = 0; r < 4; r++)
      out[base + (size_t)(q0 + quad * 4 + r) * 512 + nt * 16 + lcol] =
          f2bf(O[nt][r] * lsum[r]);
}

// ---------------------------------------------------------------------------
// layernorm over last dim (512), bf16 in; bf16 or fp32 out.
// ---------------------------------------------------------------------------
template <bool OUTF32>
__global__ __launch_bounds__(256) void ln_kernel(
    const ushort* __restrict__ h, const float* __restrict__ g,
    const float* __restrict__ beta, void* __restrict__ outv) {
  int wave = threadIdx.x >> 6, lane = threadIdx.x & 63;
  int row = blockIdx.x * 4 + wave;
  uint4 raw = *(const uint4*)(h + (size_t)row * 512 + lane * 8);
  const ushort* hu = (const ushort*)&raw;
  float vals[8];
#pragma unroll
  for (int i = 0; i < 8; i++) vals[i] = bf2f(hu[i]);
  float sum = 0.f;
#pragma unroll
  for (int i = 0; i < 8; i++) sum += vals[i];
#pragma unroll
  for (int off = 32; off >= 1; off >>= 1) sum += __shfl_xor(sum, off, 64);
  float mean = sum * (1.f / 512.f);
  float vs = 0.f;
#pragma unroll
  for (int i = 0; i < 8; i++) { float d = vals[i] - mean; vs += d * d; }
#pragma unroll
  for (int off = 32; off >= 1; off >>= 1) vs += __shfl_xor(vs, off, 64);
  float rstd = rsqrtf(vs * (1.f / 512.f) + 1e-5f);
  float4 gv0 = *(const float4*)(g + lane * 8);
  float4 gv1 = *(const float4*)(g + lane * 8 + 4);
  float4 bv0 = *(const float4*)(beta + lane * 8);
  float4 bv1 = *(const float4*)(beta + lane * 8 + 4);
  float gr[8] = {gv0.x, gv0.y, gv0.z, gv0.w, gv1.x, gv1.y, gv1.z, gv1.w};
  float br[8] = {bv0.x, bv0.y, bv0.z, bv0.w, bv1.x, bv1.y, bv1.z, bv1.w};
  float res[8];
#pragma unroll
  for (int i = 0; i < 8; i++) res[i] = (vals[i] - mean) * rstd * gr[i] + br[i];
  if (OUTF32) {
    float* op = (float*)outv + (size_t)row * 512 + lane * 8;
    float4 o0, o1;
    o0.x = res[0]; o0.y = res[1]; o0.z = res[2]; o0.w = res[3];
    o1.x = res[4]; o1.y = res[5]; o1.z = res[6]; o1.w = res[7];
    *(float4*)op = o0; *(float4*)(op + 4) = o1;
  } else {
    ushort* op = (ushort*)outv + (size_t)row * 512 + lane * 8;
    ushort4 o0, o1;
    o0.x = f2bf(res[0]); o0.y = f2bf(res[1]); o0.z = f2bf(res[2]); o0.w = f2bf(res[3]);
    o1.x = f2bf(res[4]); o1.y = f2bf(res[5]); o1.z = f2bf(res[6]); o1.w = f2bf(res[7]);
    *(ushort4*)op = o0; *(ushort4*)(op + 4) = o1;
  }
}

// ---------------------------------------------------------------------------
extern "C" void kernel_launch(void* const* d_in, const int* in_sizes, int n_in,
                              void* d_out, int out_size, void* d_ws,
                              size_t ws_size, hipStream_t stream) {
  (void)in_sizes; (void)n_in; (void)out_size; (void)ws_size;
  const float* x     = (const float*)d_in[0];
  const float* vis   = (const float*)d_in[1];
  const int*   c1    = (const int*)d_in[2];
  const int*   c2    = (const int*)d_in[3];
  const float* e1    = (const float*)d_in[4];
  const float* e2    = (const float*)d_in[5];
  const float* wq    = (const float*)d_in[6];
  const float* bq    = (const float*)d_in[7];
  const float* wk    = (const float*)d_in[8];
  const float* bk    = (const float*)d_in[9];
  const float* wv    = (const float*)d_in[10];
  const float* bv    = (const float*)d_in[11];
  const float* w1    = (const float*)d_in[12];
  const float* b1    = (const float*)d_in[13];
  const float* g1    = (const float*)d_in[14];
  const float* beta1 = (const float*)d_in[15];
  const float* w2    = (const float*)d_in[16];
  const float* b2    = (const float*)d_in[17];
  const float* g2    = (const float*)d_in[18];
  const float* beta2 = (const float*)d_in[19];
  float* out = (float*)d_out;
  ushort* ws = (ushort*)d_ws;

  const size_t BUF = (size_t)MROWS * 512;
  ushort* xp_bf  = ws;             // later h1
  ushort* vis_bf = ws + BUF;       // later attn_out
  ushort* q_bf   = ws + 2 * BUF;   // later ln1
  ushort* k_bf   = ws + 3 * BUF;   // later h2
  ushort* v_bf   = ws + 4 * BUF;
  ushort* wt_qkv = ws + 5 * BUF;
  ushort* wt1    = wt_qkv + 1536 * 512;
  ushort* wt2    = wt1 + 512 * 512;
  ushort* attn_bf = vis_bf;
  ushort* h1_bf   = xp_bf;
  ushort* ln1_bf  = q_bf;
  ushort* h2_bf   = k_bf;

  prep_kernel<<<4096, 256, 0, stream>>>(x, vis, c1, c2, e1, e2, xp_bf, vis_bf);
  wtrans_kernel<<<320, 256, 0, stream>>>(wq, wk, wv, w1, w2, wt_qkv, wt1, wt2);
  gemm_mfma<false><<<dim3(12, 64), 256, 0, stream>>>(
      vis_bf, xp_bf, wt_qkv, bq, bk, bv, q_bf, k_bf, v_bf, 0.125f);
  attn_mfma_kernel<<<1024, 256, 0, stream>>>(q_bf, k_bf, v_bf, attn_bf);
  gemm_mfma<true><<<dim3(4, 64), 256, 0, stream>>>(
      attn_bf, attn_bf, wt1, b1, b1, b1, h1_bf, h1_bf, h1_bf, 1.0f);
  ln_kernel<false><<<2048, 256, 0, stream>>>(h1_bf, g1, beta1, ln1_bf);
  gemm_mfma<true><<<dim3(4, 64), 256, 0, stream>>>(
      ln1_bf, ln1_bf, wt2, b2, b2, b2, h2_bf, h2_bf, h2_bf, 1.0f);
  ln_kernel<true><<<2048, 256, 0, stream>>>(h2_bf, g2, beta2, out);
}

// Round 4
// 290.145 us; speedup vs baseline: 6.0871x; 1.0619x over previous
//
#include <hip/hip_runtime.h>

#define DIM 512
#define SEQ 2048
#define MROWS 8192

typedef short short8 __attribute__((ext_vector_type(8)));
typedef float floatx4 __attribute__((ext_vector_type(4)));

__device__ __forceinline__ ushort f2bf(float f) {
  union { float f; unsigned u; } v; v.f = f;
  unsigned r = v.u + 0x7fff + ((v.u >> 16) & 1);
  return (ushort)(r >> 16);
}
__device__ __forceinline__ float bf2f(ushort u) {
  union { unsigned u; float f; } v; v.u = ((unsigned)u) << 16;
  return v.f;
}

// ---------------------------------------------------------------------------
// prep (blocks 0..4095): vis->bf16, xp = x + concat(emb1[c1],emb2[c2]) -> bf16
// wtrans (blocks 4096..4415): Wt[n][k] = W[k][n] bf16, wq pre-scaled 0.125
// ---------------------------------------------------------------------------
__global__ __launch_bounds__(256) void prep_wtrans_kernel(
    const float* __restrict__ x, const float* __restrict__ vis,
    const int* __restrict__ c1, const int* __restrict__ c2,
    const float* __restrict__ e1, const float* __restrict__ e2,
    const float* __restrict__ wq, const float* __restrict__ wk,
    const float* __restrict__ wv, const float* __restrict__ w1,
    const float* __restrict__ w2,
    ushort* __restrict__ xp_bf, ushort* __restrict__ vis_bf,
    ushort* __restrict__ wt_qkv, ushort* __restrict__ wt1,
    ushort* __restrict__ wt2) {
  __shared__ float Ls[64 * 65];
  if (blockIdx.x < 4096) {
    int gid = blockIdx.x * 256 + threadIdx.x;
    int row = gid >> 7;
    int col = (gid & 127) * 4;
    float4 vv = *(const float4*)(vis + (size_t)row * 512 + col);
    ushort4 vb; vb.x = f2bf(vv.x); vb.y = f2bf(vv.y); vb.z = f2bf(vv.z); vb.w = f2bf(vv.w);
    *(ushort4*)(vis_bf + (size_t)row * 512 + col) = vb;
    float4 p;
    if (col < 256) p = *(const float4*)(e1 + (size_t)c1[row] * 256 + col);
    else           p = *(const float4*)(e2 + (size_t)c2[row] * 256 + col - 256);
    float4 xv = *(const float4*)(x + (size_t)row * 512 + col);
    ushort4 xb; xb.x = f2bf(xv.x + p.x); xb.y = f2bf(xv.y + p.y);
    xb.z = f2bf(xv.z + p.z); xb.w = f2bf(xv.w + p.w);
    *(ushort4*)(xp_bf + (size_t)row * 512 + col) = xb;
  } else {
    int bid = blockIdx.x - 4096;
    int mid = bid >> 6;
    int tile = bid & 63;
    int k0 = (tile >> 3) * 64, n0 = (tile & 7) * 64;
    const float* W = mid == 0 ? wq : mid == 1 ? wk : mid == 2 ? wv : mid == 3 ? w1 : w2;
    ushort* outp = mid < 3 ? (wt_qkv + (size_t)mid * 512 * 512) : (mid == 3 ? wt1 : wt2);
    float scale = (mid == 0) ? 0.125f : 1.0f;
    int r = threadIdx.x >> 4, c4 = (threadIdx.x & 15) * 4;
#pragma unroll
    for (int i = 0; i < 4; i++) {
      int row = i * 16 + r;
      float4 wv4 = *(const float4*)(W + (size_t)(k0 + row) * 512 + n0 + c4);
      Ls[row * 65 + c4 + 0] = wv4.x * scale;
      Ls[row * 65 + c4 + 1] = wv4.y * scale;
      Ls[row * 65 + c4 + 2] = wv4.z * scale;
      Ls[row * 65 + c4 + 3] = wv4.w * scale;
    }
    __syncthreads();
    int n = threadIdx.x >> 2, kc = (threadIdx.x & 3) * 16;
    ushort pk[16];
#pragma unroll
    for (int i = 0; i < 16; i++) pk[i] = f2bf(Ls[(kc + i) * 65 + n]);
    ushort* op = outp + (size_t)(n0 + n) * 512 + k0 + kc;
    *(uint4*)op = *(uint4*)pk;
    *(uint4*)(op + 8) = *(uint4*)(pk + 8);
  }
}

// ---------------------------------------------------------------------------
// bf16 MFMA GEMM (QKV fused), 128x128 tile, BK=64, XOR-swizzled LDS,
// bf16 epilogue via LDS transpose. grid (12, 64): seg = n>>9 selects A/bias/out.
// ---------------------------------------------------------------------------
__global__ __launch_bounds__(256, 3) void gemm_mfma(
    const ushort* __restrict__ A01, const ushort* __restrict__ A2,
    const ushort* __restrict__ Wt,
    const float* __restrict__ bias0, const float* __restrict__ bias1,
    const float* __restrict__ bias2,
    ushort* __restrict__ out0, ushort* __restrict__ out1,
    ushort* __restrict__ out2, float s0scale) {
  __shared__ __align__(16) ushort As[128 * 64];
  __shared__ __align__(16) ushort Bs[128 * 64];
  int t = threadIdx.x;
  int seg = blockIdx.x >> 2;
  int nloc0 = (blockIdx.x & 3) * 128;
  int n0w = blockIdx.x * 128;
  int m0 = blockIdx.y * 128;
  const ushort* A = (seg < 2) ? A01 : A2;
  const float* bias = seg == 0 ? bias0 : seg == 1 ? bias1 : bias2;
  ushort* out = seg == 0 ? out0 : seg == 1 ? out1 : out2;
  float bscale = seg == 0 ? s0scale : 1.0f;

  int w = t >> 6, lane = t & 63;
  int wm = (w & 1) * 64, wn = (w >> 1) * 64;
  int quad = lane >> 4, lcol = lane & 15;
  int srow = t >> 3, sch = t & 7;

  floatx4 acc[4][4] = {};

  for (int k0 = 0; k0 < 512; k0 += 64) {
    __syncthreads();
#pragma unroll
    for (int i = 0; i < 4; i++) {
      int row = i * 32 + srow;
      int pofs = row * 64 + (sch ^ (row & 7)) * 8;
      *(uint4*)(&As[pofs]) =
          *(const uint4*)(A + (size_t)(m0 + row) * 512 + k0 + sch * 8);
      *(uint4*)(&Bs[pofs]) =
          *(const uint4*)(Wt + (size_t)(n0w + row) * 512 + k0 + sch * 8);
    }
    __syncthreads();
#pragma unroll
    for (int kc = 0; kc < 2; kc++) {
      int pch = ((kc * 4 + quad) ^ (lcol & 7)) * 8;
      short8 af[4], bfr[4];
#pragma unroll
      for (int i = 0; i < 4; i++) {
        af[i]  = *(const short8*)(&As[(wm + i * 16 + lcol) * 64 + pch]);
        bfr[i] = *(const short8*)(&Bs[(wn + i * 16 + lcol) * 64 + pch]);
      }
#pragma unroll
      for (int mt = 0; mt < 4; mt++)
#pragma unroll
        for (int nt = 0; nt < 4; nt++)
          acc[mt][nt] = __builtin_amdgcn_mfma_f32_16x16x32_bf16(
              af[mt], bfr[nt], acc[mt][nt], 0, 0, 0);
    }
  }

  __syncthreads();
  float* Ls = ((w & 2) ? (float*)Bs : (float*)As) + (w & 1) * 1104;
  int rr = lane >> 2, cc = (lane & 3) * 16;
#pragma unroll
  for (int mt = 0; mt < 4; mt++) {
#pragma unroll
    for (int nt = 0; nt < 4; nt++) {
      float bv = bias[nloc0 + wn + nt * 16 + lcol] * bscale;
#pragma unroll
      for (int r = 0; r < 4; r++)
        Ls[(quad * 4 + r) * 68 + nt * 16 + lcol] = acc[mt][nt][r] + bv;
    }
    asm volatile("s_waitcnt lgkmcnt(0)" ::: "memory");
    ushort pk[16];
#pragma unroll
    for (int i = 0; i < 16; i += 4) {
      float4 fv = *(const float4*)(&Ls[rr * 68 + cc + i]);
      pk[i] = f2bf(fv.x); pk[i + 1] = f2bf(fv.y);
      pk[i + 2] = f2bf(fv.z); pk[i + 3] = f2bf(fv.w);
    }
    ushort* op = out + (size_t)(m0 + wm + mt * 16 + rr) * 512 + nloc0 + wn + cc;
    *(uint4*)op = *(uint4*)pk;
    *(uint4*)(op + 8) = *(uint4*)(pk + 8);
    asm volatile("s_waitcnt lgkmcnt(0)" ::: "memory");
  }
}

// ---------------------------------------------------------------------------
// split-K GEMM for h1/h2: grid (8, 64): x&3 = n-tile, x>>2 = k-half.
// f32 partials out (no bias/act — fused into ln_fuse). 512 blocks = 2/CU.
// ---------------------------------------------------------------------------
__global__ __launch_bounds__(256, 3) void gemm_splitk(
    const ushort* __restrict__ A, const ushort* __restrict__ Wt,
    float* __restrict__ P0, float* __restrict__ P1) {
  __shared__ __align__(16) ushort As[128 * 64];
  __shared__ __align__(16) ushort Bs[128 * 64];
  int t = threadIdx.x;
  int nt0 = (blockIdx.x & 3) * 128;
  int khalf = blockIdx.x >> 2;
  int m0 = blockIdx.y * 128;
  float* Pout = khalf ? P1 : P0;
  int w = t >> 6, lane = t & 63;
  int wm = (w & 1) * 64, wn = (w >> 1) * 64;
  int quad = lane >> 4, lcol = lane & 15;
  int srow = t >> 3, sch = t & 7;
  floatx4 acc[4][4] = {};
  int kbase = khalf * 256;

  for (int k0 = kbase; k0 < kbase + 256; k0 += 64) {
    __syncthreads();
#pragma unroll
    for (int i = 0; i < 4; i++) {
      int row = i * 32 + srow;
      int pofs = row * 64 + (sch ^ (row & 7)) * 8;
      *(uint4*)(&As[pofs]) =
          *(const uint4*)(A + (size_t)(m0 + row) * 512 + k0 + sch * 8);
      *(uint4*)(&Bs[pofs]) =
          *(const uint4*)(Wt + (size_t)(nt0 + row) * 512 + k0 + sch * 8);
    }
    __syncthreads();
#pragma unroll
    for (int kc = 0; kc < 2; kc++) {
      int pch = ((kc * 4 + quad) ^ (lcol & 7)) * 8;
      short8 af[4], bfr[4];
#pragma unroll
      for (int i = 0; i < 4; i++) {
        af[i]  = *(const short8*)(&As[(wm + i * 16 + lcol) * 64 + pch]);
        bfr[i] = *(const short8*)(&Bs[(wn + i * 16 + lcol) * 64 + pch]);
      }
#pragma unroll
      for (int mt = 0; mt < 4; mt++)
#pragma unroll
        for (int nt = 0; nt < 4; nt++)
          acc[mt][nt] = __builtin_amdgcn_mfma_f32_16x16x32_bf16(
              af[mt], bfr[nt], acc[mt][nt], 0, 0, 0);
    }
  }

  __syncthreads();
  float* Ls = ((w & 2) ? (float*)Bs : (float*)As) + (w & 1) * 1104;
  int rr = lane >> 2, cc = (lane & 3) * 16;
#pragma unroll
  for (int mt = 0; mt < 4; mt++) {
#pragma unroll
    for (int nt = 0; nt < 4; nt++)
#pragma unroll
      for (int r = 0; r < 4; r++)
        Ls[(quad * 4 + r) * 68 + nt * 16 + lcol] = acc[mt][nt][r];
    asm volatile("s_waitcnt lgkmcnt(0)" ::: "memory");
    float* op = Pout + (size_t)(m0 + wm + mt * 16 + rr) * 512 + nt0 + wn + cc;
#pragma unroll
    for (int i = 0; i < 16; i += 4)
      *(float4*)(op + i) = *(const float4*)(&Ls[rr * 68 + cc + i]);
    asm volatile("s_waitcnt lgkmcnt(0)" ::: "memory");
  }
}

// ---------------------------------------------------------------------------
// MFMA flash attention, static-max softmax, 128 q-rows/block (wave = 32),
// K-tile 128, swizzled LDS. grid 512 (= 2 blocks/CU), 256 threads.
// ---------------------------------------------------------------------------
__global__ __launch_bounds__(256, 2) void attn_mfma_kernel(
    const ushort* __restrict__ q, const ushort* __restrict__ k,
    const ushort* __restrict__ v, ushort* __restrict__ out) {
  __shared__ __align__(16) ushort Ks[128 * 64];    // [krow][dim] swizzled
  __shared__ __align__(16) ushort Vt[64 * 128];    // [dim][krow] swizzled
  __shared__ __align__(16) ushort Ps[4 * 32 * 64]; // wave-private P (half-tile)
  int t = threadIdx.x;
  int blk = blockIdx.x;
  int qt = blk & 15, h = (blk >> 4) & 7, b = blk >> 7;
  int wave = t >> 6, lane = t & 63, quad = lane >> 4, lcol = lane & 15;
  int q0 = qt * 128 + wave * 32;
  const size_t base = (size_t)b * SEQ * 512 + h * 64;

  short8 qf[2][2];
#pragma unroll
  for (int qm = 0; qm < 2; qm++)
#pragma unroll
    for (int kc = 0; kc < 2; kc++)
      qf[qm][kc] = *(const short8*)(
          q + base + (size_t)(q0 + qm * 16 + lcol) * 512 + kc * 32 + quad * 8);

  floatx4 O[2][4] = {};
  float lsum[2][4] = {};

  ushort* Pw = Ps + wave * (32 * 64);
  int krow = t >> 1, khalf = t & 1;
  int pl = t & 63, dg = t >> 6;

  for (int kt = 0; kt < SEQ; kt += 128) {
    __syncthreads();
#pragma unroll
    for (int j = 0; j < 4; j++) {
      int ch = khalf * 4 + j;
      *(uint4*)(&Ks[krow * 64 + (ch ^ (krow & 7)) * 8]) =
          *(const uint4*)(k + base + (size_t)(kt + krow) * 512 + ch * 8);
    }
    {
      uint4 va[2], vb[2];
      const ushort* vr0 = v + base + (size_t)(kt + 2 * pl) * 512 + dg * 16;
      const ushort* vr1 = vr0 + 512;
      va[0] = *(const uint4*)(vr0); va[1] = *(const uint4*)(vr0 + 8);
      vb[0] = *(const uint4*)(vr1); vb[1] = *(const uint4*)(vr1 + 8);
      const ushort* a0 = (const ushort*)va;
      const ushort* a1 = (const ushort*)vb;
#pragma unroll
      for (int i = 0; i < 16; i++) {
        int dim = dg * 16 + i;
        unsigned pack = (unsigned)a0[i] | ((unsigned)a1[i] << 16);
        int pch = (pl >> 2) ^ (dim & 7);
        *(unsigned*)(&Vt[dim * 128 + pch * 8 + (pl & 3) * 2]) = pack;
      }
    }
    __syncthreads();

#pragma unroll
    for (int half = 0; half < 2; half++) {
#pragma unroll
      for (int qm = 0; qm < 2; qm++) {
        floatx4 S[4] = {};
#pragma unroll
        for (int kc = 0; kc < 2; kc++) {
          int pch = ((kc * 4 + quad) ^ (lcol & 7)) * 8;
#pragma unroll
          for (int jt4 = 0; jt4 < 4; jt4++) {
            int jrow = (half * 4 + jt4) * 16 + lcol;
            short8 kf = *(const short8*)(&Ks[jrow * 64 + pch]);
            S[jt4] = __builtin_amdgcn_mfma_f32_16x16x32_bf16(
                qf[qm][kc], kf, S[jt4], 0, 0, 0);
          }
        }
#pragma unroll
        for (int jt4 = 0; jt4 < 4; jt4++)
#pragma unroll
          for (int r = 0; r < 4; r++) {
            float p = __expf(S[jt4][r]);
            lsum[qm][r] += p;
            int prow = qm * 16 + quad * 4 + r;
            int pcol = jt4 * 16 + lcol;
            int pch2 = (pcol >> 3) ^ (prow & 7);
            Pw[prow * 64 + pch2 * 8 + (pcol & 7)] =
                (ushort)(__float_as_uint(p) >> 16);
          }
      }
      asm volatile("s_waitcnt lgkmcnt(0)" ::: "memory");
#pragma unroll
      for (int qm = 0; qm < 2; qm++) {
#pragma unroll
        for (int kc = 0; kc < 2; kc++) {
          short8 pf = *(const short8*)(
              &Pw[(qm * 16 + lcol) * 64 + ((kc * 4 + quad) ^ (lcol & 7)) * 8]);
#pragma unroll
          for (int nt = 0; nt < 4; nt++) {
            int dim = nt * 16 + lcol;
            int ch = half * 8 + kc * 4 + quad;
            short8 vf = *(const short8*)(&Vt[dim * 128 + (ch ^ (lcol & 7)) * 8]);
            O[qm][nt] = __builtin_amdgcn_mfma_f32_16x16x32_bf16(
                pf, vf, O[qm][nt], 0, 0, 0);
          }
        }
      }
    }
  }

#pragma unroll
  for (int qm = 0; qm < 2; qm++)
#pragma unroll
    for (int r = 0; r < 4; r++) {
#pragma unroll
      for (int m = 1; m <= 8; m <<= 1)
        lsum[qm][r] += __shfl_xor(lsum[qm][r], m, 64);
      lsum[qm][r] = 1.f / lsum[qm][r];
    }
#pragma unroll
  for (int qm = 0; qm < 2; qm++)
#pragma unroll
    for (int nt = 0; nt < 4; nt++)
#pragma unroll
      for (int r = 0; r < 4; r++)
        out[base + (size_t)(q0 + qm * 16 + quad * 4 + r) * 512 + nt * 16 + lcol] =
            f2bf(O[qm][nt][r] * lsum[qm][r]);
}

// ---------------------------------------------------------------------------
// fused: h = leaky(P0 + P1 + bias); layernorm(h) -> bf16 or f32
// ---------------------------------------------------------------------------
template <bool OUTF32>
__global__ __launch_bounds__(256) void ln_fuse(
    const float* __restrict__ P0, const float* __restrict__ P1,
    const float* __restrict__ bias, const float* __restrict__ g,
    const float* __restrict__ beta, void* __restrict__ outv) {
  int wave = threadIdx.x >> 6, lane = threadIdx.x & 63;
  int row = blockIdx.x * 4 + wave;
  const float* p0 = P0 + (size_t)row * 512 + lane * 8;
  const float* p1 = P1 + (size_t)row * 512 + lane * 8;
  float4 a0 = *(const float4*)(p0), a1 = *(const float4*)(p0 + 4);
  float4 b0 = *(const float4*)(p1), b1 = *(const float4*)(p1 + 4);
  float4 c0 = *(const float4*)(bias + lane * 8);
  float4 c1 = *(const float4*)(bias + lane * 8 + 4);
  float vals[8] = {a0.x + b0.x + c0.x, a0.y + b0.y + c0.y,
                   a0.z + b0.z + c0.z, a0.w + b0.w + c0.w,
                   a1.x + b1.x + c1.x, a1.y + b1.y + c1.y,
                   a1.z + b1.z + c1.z, a1.w + b1.w + c1.w};
#pragma unroll
  for (int i = 0; i < 8; i++) vals[i] = vals[i] >= 0.f ? vals[i] : 0.2f * vals[i];
  float sum = 0.f;
#pragma unroll
  for (int i = 0; i < 8; i++) sum += vals[i];
#pragma unroll
  for (int off = 32; off >= 1; off >>= 1) sum += __shfl_xor(sum, off, 64);
  float mean = sum * (1.f / 512.f);
  float vs = 0.f;
#pragma unroll
  for (int i = 0; i < 8; i++) { float d = vals[i] - mean; vs += d * d; }
#pragma unroll
  for (int off = 32; off >= 1; off >>= 1) vs += __shfl_xor(vs, off, 64);
  float rstd = rsqrtf(vs * (1.f / 512.f) + 1e-5f);
  float4 gv0 = *(const float4*)(g + lane * 8);
  float4 gv1 = *(const float4*)(g + lane * 8 + 4);
  float4 bv0 = *(const float4*)(beta + lane * 8);
  float4 bv1 = *(const float4*)(beta + lane * 8 + 4);
  float gr[8] = {gv0.x, gv0.y, gv0.z, gv0.w, gv1.x, gv1.y, gv1.z, gv1.w};
  float br[8] = {bv0.x, bv0.y, bv0.z, bv0.w, bv1.x, bv1.y, bv1.z, bv1.w};
  float res[8];
#pragma unroll
  for (int i = 0; i < 8; i++) res[i] = (vals[i] - mean) * rstd * gr[i] + br[i];
  if (OUTF32) {
    float* op = (float*)outv + (size_t)row * 512 + lane * 8;
    float4 o0, o1;
    o0.x = res[0]; o0.y = res[1]; o0.z = res[2]; o0.w = res[3];
    o1.x = res[4]; o1.y = res[5]; o1.z = res[6]; o1.w = res[7];
    *(float4*)op = o0; *(float4*)(op + 4) = o1;
  } else {
    ushort* op = (ushort*)outv + (size_t)row * 512 + lane * 8;
    ushort4 o0, o1;
    o0.x = f2bf(res[0]); o0.y = f2bf(res[1]); o0.z = f2bf(res[2]); o0.w = f2bf(res[3]);
    o1.x = f2bf(res[4]); o1.y = f2bf(res[5]); o1.z = f2bf(res[6]); o1.w = f2bf(res[7]);
    *(ushort4*)op = o0; *(ushort4*)(op + 4) = o1;
  }
}

// ---------------------------------------------------------------------------
extern "C" void kernel_launch(void* const* d_in, const int* in_sizes, int n_in,
                              void* d_out, int out_size, void* d_ws,
                              size_t ws_size, hipStream_t stream) {
  (void)in_sizes; (void)n_in; (void)out_size; (void)ws_size;
  const float* x     = (const float*)d_in[0];
  const float* vis   = (const float*)d_in[1];
  const int*   c1    = (const int*)d_in[2];
  const int*   c2    = (const int*)d_in[3];
  const float* e1    = (const float*)d_in[4];
  const float* e2    = (const float*)d_in[5];
  const float* wq    = (const float*)d_in[6];
  const float* bq    = (const float*)d_in[7];
  const float* wk    = (const float*)d_in[8];
  const float* bk    = (const float*)d_in[9];
  const float* wv    = (const float*)d_in[10];
  const float* bv    = (const float*)d_in[11];
  const float* w1    = (const float*)d_in[12];
  const float* b1    = (const float*)d_in[13];
  const float* g1    = (const float*)d_in[14];
  const float* beta1 = (const float*)d_in[15];
  const float* w2    = (const float*)d_in[16];
  const float* b2    = (const float*)d_in[17];
  const float* g2    = (const float*)d_in[18];
  const float* beta2 = (const float*)d_in[19];
  float* out = (float*)d_out;
  ushort* ws = (ushort*)d_ws;

  const size_t BUF = (size_t)MROWS * 512;  // 4,194,304 elements
  ushort* xp_bf  = ws;             // later ln1
  ushort* vis_bf = ws + BUF;       // later attn_out
  ushort* q_bf   = ws + 2 * BUF;
  ushort* k_bf   = ws + 3 * BUF;
  ushort* v_bf   = ws + 4 * BUF;
  float*  P0     = (float*)(ws + 2 * BUF);  // overlays q,k (dead after attn)
  float*  P1     = (float*)(ws + 4 * BUF);  // overlays v + 1 BUF
  ushort* wt_qkv = ws + 6 * BUF;
  ushort* wt1    = wt_qkv + 1536 * 512;
  ushort* wt2    = wt1 + 512 * 512;
  ushort* attn_bf = vis_bf;
  ushort* ln1_bf  = xp_bf;

  prep_wtrans_kernel<<<4416, 256, 0, stream>>>(
      x, vis, c1, c2, e1, e2, wq, wk, wv, w1, w2, xp_bf, vis_bf, wt_qkv, wt1, wt2);
  gemm_mfma<<<dim3(12, 64), 256, 0, stream>>>(
      vis_bf, xp_bf, wt_qkv, bq, bk, bv, q_bf, k_bf, v_bf, 0.125f);
  attn_mfma_kernel<<<512, 256, 0, stream>>>(q_bf, k_bf, v_bf, attn_bf);
  gemm_splitk<<<dim3(8, 64), 256, 0, stream>>>(attn_bf, wt1, P0, P1);
  ln_fuse<false><<<2048, 256, 0, stream>>>(P0, P1, b1, g1, beta1, ln1_bf);
  gemm_splitk<<<dim3(8, 64), 256, 0, stream>>>(ln1_bf, wt2, P0, P1);
  ln_fuse<true><<<2048, 256, 0, stream>>>(P0, P1, b2, g2, beta2, out);
}

// Round 5
// 271.959 us; speedup vs baseline: 6.4942x; 1.0669x over previous
//
#include <hip/hip_runtime.h>

#define DIM 512
#define SEQ 2048
#define MROWS 8192

typedef short short8 __attribute__((ext_vector_type(8)));
typedef float floatx4 __attribute__((ext_vector_type(4)));

__device__ __forceinline__ ushort f2bf(float f) {
  union { float f; unsigned u; } v; v.f = f;
  unsigned r = v.u + 0x7fff + ((v.u >> 16) & 1);
  return (ushort)(r >> 16);
}
__device__ __forceinline__ float bf2f(ushort u) {
  union { unsigned u; float f; } v; v.u = ((unsigned)u) << 16;
  return v.f;
}

// ---------------------------------------------------------------------------
// prep (blocks 0..4095): vis->bf16, xp = x + concat(emb1[c1],emb2[c2]) -> bf16
// wtrans (blocks 4096..4415): Wt[n][k] = W[k][n] bf16, wq pre-scaled 0.125
// ---------------------------------------------------------------------------
__global__ __launch_bounds__(256) void prep_wtrans_kernel(
    const float* __restrict__ x, const float* __restrict__ vis,
    const int* __restrict__ c1, const int* __restrict__ c2,
    const float* __restrict__ e1, const float* __restrict__ e2,
    const float* __restrict__ wq, const float* __restrict__ wk,
    const float* __restrict__ wv, const float* __restrict__ w1,
    const float* __restrict__ w2,
    ushort* __restrict__ xp_bf, ushort* __restrict__ vis_bf,
    ushort* __restrict__ wt_qkv, ushort* __restrict__ wt1,
    ushort* __restrict__ wt2) {
  __shared__ float Ls[64 * 65];
  if (blockIdx.x < 4096) {
    int gid = blockIdx.x * 256 + threadIdx.x;
    int row = gid >> 7;
    int col = (gid & 127) * 4;
    float4 vv = *(const float4*)(vis + (size_t)row * 512 + col);
    ushort4 vb; vb.x = f2bf(vv.x); vb.y = f2bf(vv.y); vb.z = f2bf(vv.z); vb.w = f2bf(vv.w);
    *(ushort4*)(vis_bf + (size_t)row * 512 + col) = vb;
    float4 p;
    if (col < 256) p = *(const float4*)(e1 + (size_t)c1[row] * 256 + col);
    else           p = *(const float4*)(e2 + (size_t)c2[row] * 256 + col - 256);
    float4 xv = *(const float4*)(x + (size_t)row * 512 + col);
    ushort4 xb; xb.x = f2bf(xv.x + p.x); xb.y = f2bf(xv.y + p.y);
    xb.z = f2bf(xv.z + p.z); xb.w = f2bf(xv.w + p.w);
    *(ushort4*)(xp_bf + (size_t)row * 512 + col) = xb;
  } else {
    int bid = blockIdx.x - 4096;
    int mid = bid >> 6;
    int tile = bid & 63;
    int k0 = (tile >> 3) * 64, n0 = (tile & 7) * 64;
    const float* W = mid == 0 ? wq : mid == 1 ? wk : mid == 2 ? wv : mid == 3 ? w1 : w2;
    ushort* outp = mid < 3 ? (wt_qkv + (size_t)mid * 512 * 512) : (mid == 3 ? wt1 : wt2);
    float scale = (mid == 0) ? 0.125f : 1.0f;
    int r = threadIdx.x >> 4, c4 = (threadIdx.x & 15) * 4;
#pragma unroll
    for (int i = 0; i < 4; i++) {
      int row = i * 16 + r;
      float4 wv4 = *(const float4*)(W + (size_t)(k0 + row) * 512 + n0 + c4);
      Ls[row * 65 + c4 + 0] = wv4.x * scale;
      Ls[row * 65 + c4 + 1] = wv4.y * scale;
      Ls[row * 65 + c4 + 2] = wv4.z * scale;
      Ls[row * 65 + c4 + 3] = wv4.w * scale;
    }
    __syncthreads();
    int n = threadIdx.x >> 2, kc = (threadIdx.x & 3) * 16;
    ushort pk[16];
#pragma unroll
    for (int i = 0; i < 16; i++) pk[i] = f2bf(Ls[(kc + i) * 65 + n]);
    ushort* op = outp + (size_t)(n0 + n) * 512 + k0 + kc;
    *(uint4*)op = *(uint4*)pk;
    *(uint4*)(op + 8) = *(uint4*)(pk + 8);
  }
}

// ---------------------------------------------------------------------------
// bf16 MFMA GEMM, 64x128 (MxN) tile, BK=64, XOR-swizzled LDS, bias (+leaky)
// epilogue via LDS transpose -> bf16 dwordx4 stores.
// grid (nchunks, 128). seg = n>>9 selects A/bias/out (QKV fusion).
// 4 waves in 2x2: wave tile 32m x 64n. MFMA:ds_read = 16:6 per BK.
// ---------------------------------------------------------------------------
template <bool LEAKY>
__global__ __launch_bounds__(256, 4) void gemm_mfma(
    const ushort* __restrict__ A01, const ushort* __restrict__ A2,
    const ushort* __restrict__ Wt,
    const float* __restrict__ bias0, const float* __restrict__ bias1,
    const float* __restrict__ bias2,
    ushort* __restrict__ out0, ushort* __restrict__ out1,
    ushort* __restrict__ out2, float s0scale) {
  __shared__ __align__(16) ushort Sm[12288];  // As 64x64 | Bs 128x64 = 24 KB
  ushort* As = Sm;
  ushort* Bs = Sm + 4096;
  int t = threadIdx.x;
  int seg = blockIdx.x >> 2;
  int nloc0 = (blockIdx.x & 3) * 128;
  int n0w = blockIdx.x * 128;
  int m0 = blockIdx.y * 64;
  const ushort* A = (seg < 2) ? A01 : A2;
  const float* bias = seg == 0 ? bias0 : seg == 1 ? bias1 : bias2;
  ushort* out = seg == 0 ? out0 : seg == 1 ? out1 : out2;
  float bscale = seg == 0 ? s0scale : 1.0f;

  int w = t >> 6, lane = t & 63;
  int wm = (w & 1) * 32, wn = (w >> 1) * 64;
  int quad = lane >> 4, lcol = lane & 15;
  int arow = t >> 2, ach = (t & 3) * 2;   // A staging: 2 uint4/thread
  int brow = t >> 1, bch = (t & 1) * 4;   // B staging: 4 uint4/thread

  floatx4 acc[2][4] = {};

  for (int k0 = 0; k0 < 512; k0 += 64) {
    __syncthreads();
#pragma unroll
    for (int i = 0; i < 2; i++) {
      int ch = ach + i;
      *(uint4*)(&As[arow * 64 + (ch ^ (arow & 7)) * 8]) =
          *(const uint4*)(A + (size_t)(m0 + arow) * 512 + k0 + ch * 8);
    }
#pragma unroll
    for (int j = 0; j < 4; j++) {
      int ch = bch + j;
      *(uint4*)(&Bs[brow * 64 + (ch ^ (brow & 7)) * 8]) =
          *(const uint4*)(Wt + (size_t)(n0w + brow) * 512 + k0 + ch * 8);
    }
    __syncthreads();
#pragma unroll
    for (int kc = 0; kc < 2; kc++) {
      int pch = ((kc * 4 + quad) ^ (lcol & 7)) * 8;
      short8 af[2], bfr[4];
#pragma unroll
      for (int i = 0; i < 2; i++)
        af[i] = *(const short8*)(&As[(wm + i * 16 + lcol) * 64 + pch]);
#pragma unroll
      for (int i = 0; i < 4; i++)
        bfr[i] = *(const short8*)(&Bs[(wn + i * 16 + lcol) * 64 + pch]);
#pragma unroll
      for (int mt = 0; mt < 2; mt++)
#pragma unroll
        for (int nt = 0; nt < 4; nt++)
          acc[mt][nt] = __builtin_amdgcn_mfma_f32_16x16x32_bf16(
              af[mt], bfr[nt], acc[mt][nt], 0, 0, 0);
    }
  }

  // epilogue: wave-private LDS transpose -> coalesced 16B bf16 stores
  __syncthreads();
  float* Ls = (float*)Sm + w * 1088;  // 16x68 f32 per wave
  int rr = lane >> 2, cc = (lane & 3) * 16;
#pragma unroll
  for (int mt = 0; mt < 2; mt++) {
#pragma unroll
    for (int nt = 0; nt < 4; nt++) {
      float bv = bias[nloc0 + wn + nt * 16 + lcol] * bscale;
#pragma unroll
      for (int r = 0; r < 4; r++) {
        float vv = acc[mt][nt][r] + bv;
        if (LEAKY) vv = vv >= 0.f ? vv : 0.2f * vv;
        Ls[(quad * 4 + r) * 68 + nt * 16 + lcol] = vv;
      }
    }
    asm volatile("s_waitcnt lgkmcnt(0)" ::: "memory");
    ushort pk[16];
#pragma unroll
    for (int i = 0; i < 16; i += 4) {
      float4 fv = *(const float4*)(&Ls[rr * 68 + cc + i]);
      pk[i] = f2bf(fv.x); pk[i + 1] = f2bf(fv.y);
      pk[i + 2] = f2bf(fv.z); pk[i + 3] = f2bf(fv.w);
    }
    ushort* op = out + (size_t)(m0 + wm + mt * 16 + rr) * 512 + nloc0 + wn + cc;
    *(uint4*)op = *(uint4*)pk;
    *(uint4*)(op + 8) = *(uint4*)(pk + 8);
    asm volatile("s_waitcnt lgkmcnt(0)" ::: "memory");
  }
}

// ---------------------------------------------------------------------------
// MFMA flash attention, static-max softmax, 128 q-rows/block (wave = 32),
// K-tile 128, swizzled LDS. grid 512 (= 2 blocks/CU), 256 threads.
// ---------------------------------------------------------------------------
__global__ __launch_bounds__(256, 2) void attn_mfma_kernel(
    const ushort* __restrict__ q, const ushort* __restrict__ k,
    const ushort* __restrict__ v, ushort* __restrict__ out) {
  __shared__ __align__(16) ushort Ks[128 * 64];    // [krow][dim] swizzled
  __shared__ __align__(16) ushort Vt[64 * 128];    // [dim][krow] swizzled
  __shared__ __align__(16) ushort Ps[4 * 32 * 64]; // wave-private P (half-tile)
  int t = threadIdx.x;
  int blk = blockIdx.x;
  int qt = blk & 15, h = (blk >> 4) & 7, b = blk >> 7;
  int wave = t >> 6, lane = t & 63, quad = lane >> 4, lcol = lane & 15;
  int q0 = qt * 128 + wave * 32;
  const size_t base = (size_t)b * SEQ * 512 + h * 64;

  short8 qf[2][2];
#pragma unroll
  for (int qm = 0; qm < 2; qm++)
#pragma unroll
    for (int kc = 0; kc < 2; kc++)
      qf[qm][kc] = *(const short8*)(
          q + base + (size_t)(q0 + qm * 16 + lcol) * 512 + kc * 32 + quad * 8);

  floatx4 O[2][4] = {};
  float lsum[2][4] = {};

  ushort* Pw = Ps + wave * (32 * 64);
  int krow = t >> 1, khalf = t & 1;
  int pl = t & 63, dg = t >> 6;

  for (int kt = 0; kt < SEQ; kt += 128) {
    __syncthreads();
#pragma unroll
    for (int j = 0; j < 4; j++) {
      int ch = khalf * 4 + j;
      *(uint4*)(&Ks[krow * 64 + (ch ^ (krow & 7)) * 8]) =
          *(const uint4*)(k + base + (size_t)(kt + krow) * 512 + ch * 8);
    }
    {
      uint4 va[2], vb[2];
      const ushort* vr0 = v + base + (size_t)(kt + 2 * pl) * 512 + dg * 16;
      const ushort* vr1 = vr0 + 512;
      va[0] = *(const uint4*)(vr0); va[1] = *(const uint4*)(vr0 + 8);
      vb[0] = *(const uint4*)(vr1); vb[1] = *(const uint4*)(vr1 + 8);
      const ushort* a0 = (const ushort*)va;
      const ushort* a1 = (const ushort*)vb;
#pragma unroll
      for (int i = 0; i < 16; i++) {
        int dim = dg * 16 + i;
        unsigned pack = (unsigned)a0[i] | ((unsigned)a1[i] << 16);
        int pch = (pl >> 2) ^ (dim & 7);
        *(unsigned*)(&Vt[dim * 128 + pch * 8 + (pl & 3) * 2]) = pack;
      }
    }
    __syncthreads();

#pragma unroll
    for (int half = 0; half < 2; half++) {
#pragma unroll
      for (int qm = 0; qm < 2; qm++) {
        floatx4 S[4] = {};
#pragma unroll
        for (int kc = 0; kc < 2; kc++) {
          int pch = ((kc * 4 + quad) ^ (lcol & 7)) * 8;
#pragma unroll
          for (int jt4 = 0; jt4 < 4; jt4++) {
            int jrow = (half * 4 + jt4) * 16 + lcol;
            short8 kf = *(const short8*)(&Ks[jrow * 64 + pch]);
            S[jt4] = __builtin_amdgcn_mfma_f32_16x16x32_bf16(
                qf[qm][kc], kf, S[jt4], 0, 0, 0);
          }
        }
#pragma unroll
        for (int jt4 = 0; jt4 < 4; jt4++)
#pragma unroll
          for (int r = 0; r < 4; r++) {
            float p = __expf(S[jt4][r]);
            lsum[qm][r] += p;
            int prow = qm * 16 + quad * 4 + r;
            int pcol = jt4 * 16 + lcol;
            int pch2 = (pcol >> 3) ^ (prow & 7);
            Pw[prow * 64 + pch2 * 8 + (pcol & 7)] =
                (ushort)(__float_as_uint(p) >> 16);
          }
      }
      asm volatile("s_waitcnt lgkmcnt(0)" ::: "memory");
#pragma unroll
      for (int qm = 0; qm < 2; qm++) {
#pragma unroll
        for (int kc = 0; kc < 2; kc++) {
          short8 pf = *(const short8*)(
              &Pw[(qm * 16 + lcol) * 64 + ((kc * 4 + quad) ^ (lcol & 7)) * 8]);
#pragma unroll
          for (int nt = 0; nt < 4; nt++) {
            int dim = nt * 16 + lcol;
            int ch = half * 8 + kc * 4 + quad;
            short8 vf = *(const short8*)(&Vt[dim * 128 + (ch ^ (lcol & 7)) * 8]);
            O[qm][nt] = __builtin_amdgcn_mfma_f32_16x16x32_bf16(
                pf, vf, O[qm][nt], 0, 0, 0);
          }
        }
      }
    }
  }

#pragma unroll
  for (int qm = 0; qm < 2; qm++)
#pragma unroll
    for (int r = 0; r < 4; r++) {
#pragma unroll
      for (int m = 1; m <= 8; m <<= 1)
        lsum[qm][r] += __shfl_xor(lsum[qm][r], m, 64);
      lsum[qm][r] = 1.f / lsum[qm][r];
    }
#pragma unroll
  for (int qm = 0; qm < 2; qm++)
#pragma unroll
    for (int nt = 0; nt < 4; nt++)
#pragma unroll
      for (int r = 0; r < 4; r++)
        out[base + (size_t)(q0 + qm * 16 + quad * 4 + r) * 512 + nt * 16 + lcol] =
            f2bf(O[qm][nt][r] * lsum[qm][r]);
}

// ---------------------------------------------------------------------------
// layernorm over last dim (512), bf16 in; bf16 or fp32 out.
// ---------------------------------------------------------------------------
template <bool OUTF32>
__global__ __launch_bounds__(256) void ln_kernel(
    const ushort* __restrict__ h, const float* __restrict__ g,
    const float* __restrict__ beta, void* __restrict__ outv) {
  int wave = threadIdx.x >> 6, lane = threadIdx.x & 63;
  int row = blockIdx.x * 4 + wave;
  uint4 raw = *(const uint4*)(h + (size_t)row * 512 + lane * 8);
  const ushort* hu = (const ushort*)&raw;
  float vals[8];
#pragma unroll
  for (int i = 0; i < 8; i++) vals[i] = bf2f(hu[i]);
  float sum = 0.f;
#pragma unroll
  for (int i = 0; i < 8; i++) sum += vals[i];
#pragma unroll
  for (int off = 32; off >= 1; off >>= 1) sum += __shfl_xor(sum, off, 64);
  float mean = sum * (1.f / 512.f);
  float vs = 0.f;
#pragma unroll
  for (int i = 0; i < 8; i++) { float d = vals[i] - mean; vs += d * d; }
#pragma unroll
  for (int off = 32; off >= 1; off >>= 1) vs += __shfl_xor(vs, off, 64);
  float rstd = rsqrtf(vs * (1.f / 512.f) + 1e-5f);
  float4 gv0 = *(const float4*)(g + lane * 8);
  float4 gv1 = *(const float4*)(g + lane * 8 + 4);
  float4 bv0 = *(const float4*)(beta + lane * 8);
  float4 bv1 = *(const float4*)(beta + lane * 8 + 4);
  float gr[8] = {gv0.x, gv0.y, gv0.z, gv0.w, gv1.x, gv1.y, gv1.z, gv1.w};
  float br[8] = {bv0.x, bv0.y, bv0.z, bv0.w, bv1.x, bv1.y, bv1.z, bv1.w};
  float res[8];
#pragma unroll
  for (int i = 0; i < 8; i++) res[i] = (vals[i] - mean) * rstd * gr[i] + br[i];
  if (OUTF32) {
    float* op = (float*)outv + (size_t)row * 512 + lane * 8;
    float4 o0, o1;
    o0.x = res[0]; o0.y = res[1]; o0.z = res[2]; o0.w = res[3];
    o1.x = res[4]; o1.y = res[5]; o1.z = res[6]; o1.w = res[7];
    *(float4*)op = o0; *(float4*)(op + 4) = o1;
  } else {
    ushort* op = (ushort*)outv + (size_t)row * 512 + lane * 8;
    ushort4 o0, o1;
    o0.x = f2bf(res[0]); o0.y = f2bf(res[1]); o0.z = f2bf(res[2]); o0.w = f2bf(res[3]);
    o1.x = f2bf(res[4]); o1.y = f2bf(res[5]); o1.z = f2bf(res[6]); o1.w = f2bf(res[7]);
    *(ushort4*)op = o0; *(ushort4*)(op + 4) = o1;
  }
}

// ---------------------------------------------------------------------------
extern "C" void kernel_launch(void* const* d_in, const int* in_sizes, int n_in,
                              void* d_out, int out_size, void* d_ws,
                              size_t ws_size, hipStream_t stream) {
  (void)in_sizes; (void)n_in; (void)out_size; (void)ws_size;
  const float* x     = (const float*)d_in[0];
  const float* vis   = (const float*)d_in[1];
  const int*   c1    = (const int*)d_in[2];
  const int*   c2    = (const int*)d_in[3];
  const float* e1    = (const float*)d_in[4];
  const float* e2    = (const float*)d_in[5];
  const float* wq    = (const float*)d_in[6];
  const float* bq    = (const float*)d_in[7];
  const float* wk    = (const float*)d_in[8];
  const float* bk    = (const float*)d_in[9];
  const float* wv    = (const float*)d_in[10];
  const float* bv    = (const float*)d_in[11];
  const float* w1    = (const float*)d_in[12];
  const float* b1    = (const float*)d_in[13];
  const float* g1    = (const float*)d_in[14];
  const float* beta1 = (const float*)d_in[15];
  const float* w2    = (const float*)d_in[16];
  const float* b2    = (const float*)d_in[17];
  const float* g2    = (const float*)d_in[18];
  const float* beta2 = (const float*)d_in[19];
  float* out = (float*)d_out;
  ushort* ws = (ushort*)d_ws;

  const size_t BUF = (size_t)MROWS * 512;
  ushort* xp_bf  = ws;             // later h1
  ushort* vis_bf = ws + BUF;       // later attn_out
  ushort* q_bf   = ws + 2 * BUF;   // later ln1
  ushort* k_bf   = ws + 3 * BUF;   // later h2
  ushort* v_bf   = ws + 4 * BUF;
  ushort* wt_qkv = ws + 5 * BUF;
  ushort* wt1    = wt_qkv + 1536 * 512;
  ushort* wt2    = wt1 + 512 * 512;
  ushort* attn_bf = vis_bf;
  ushort* h1_bf   = xp_bf;
  ushort* ln1_bf  = q_bf;
  ushort* h2_bf   = k_bf;

  prep_wtrans_kernel<<<4416, 256, 0, stream>>>(
      x, vis, c1, c2, e1, e2, wq, wk, wv, w1, w2, xp_bf, vis_bf, wt_qkv, wt1, wt2);
  gemm_mfma<false><<<dim3(12, 128), 256, 0, stream>>>(
      vis_bf, xp_bf, wt_qkv, bq, bk, bv, q_bf, k_bf, v_bf, 0.125f);
  attn_mfma_kernel<<<512, 256, 0, stream>>>(q_bf, k_bf, v_bf, attn_bf);
  gemm_mfma<true><<<dim3(4, 128), 256, 0, stream>>>(
      attn_bf, attn_bf, wt1, b1, b1, b1, h1_bf, h1_bf, h1_bf, 1.0f);
  ln_kernel<false><<<2048, 256, 0, stream>>>(h1_bf, g1, beta1, ln1_bf);
  gemm_mfma<true><<<dim3(4, 128), 256, 0, stream>>>(
      ln1_bf, ln1_bf, wt2, b2, b2, b2, h2_bf, h2_bf, h2_bf, 1.0f);
  ln_kernel<true><<<2048, 256, 0, stream>>>(h2_bf, g2, beta2, out);
}